// Round 15
// baseline (322.983 us; speedup 1.0000x reference)
//
#include <hip/hip_runtime.h>

typedef unsigned short u16;
typedef unsigned int u32;
typedef __attribute__((ext_vector_type(8))) u16 u16x8;
typedef __attribute__((ext_vector_type(4))) u16 u16x4;
typedef __attribute__((ext_vector_type(8))) __bf16 bf16x8;
typedef __attribute__((ext_vector_type(4))) float f32x4;

static __device__ __forceinline__ float bf2f(u16 u) {
    union { u32 i; float f; } v; v.i = ((u32)u) << 16; return v.f;
}
static __device__ __forceinline__ u16 f2bf(float f) {   // manual RNE (cold paths)
    union { float f; u32 i; } v; v.f = f;
    u32 r = v.i + 0x7fffu + ((v.i >> 16) & 1u);
    return (u16)(r >> 16);
}
static __device__ __forceinline__ u16 f2bfn(float f) {  // native cvt (hot paths)
    __bf16 h = (__bf16)f;
    return *(u16*)&h;
}
// async global -> LDS, 16B per lane; ldst must be wave-uniform (HW adds lane*16)
static __device__ __forceinline__ void gl_lds16(const void* gsrc, void* ldst) {
    __builtin_amdgcn_global_load_lds((const __attribute__((address_space(1))) void*)gsrc,
                                     (__attribute__((address_space(3))) void*)ldst, 16, 0, 0);
}

// ---------------- weight transpose + fp32->bf16 convert: out[n][k] = in[k][n]
// batched 1024x1024 variant: z selects (wq,wk,wv,wo)
__global__ __launch_bounds__(256) void transpose_cvt4(const float* __restrict__ w0, const float* __restrict__ w1,
                                                      const float* __restrict__ w2, const float* __restrict__ w3,
                                                      u16* __restrict__ o0, u16* __restrict__ o1,
                                                      u16* __restrict__ o2, u16* __restrict__ o3) {
    __shared__ float t[32][33];
    const float* in; u16* out;
    switch (blockIdx.z) {
        case 0:  in = w0; out = o0; break;
        case 1:  in = w1; out = o1; break;
        case 2:  in = w2; out = o2; break;
        default: in = w3; out = o3; break;
    }
    int k0 = blockIdx.y << 5, n0 = blockIdx.x << 5;
    int r = threadIdx.x >> 3, c4 = threadIdx.x & 7;
    float4 v = *(const float4*)(in + (size_t)(k0 + r) * 1024 + n0 + (c4 << 2));
    t[r][c4 * 4 + 0] = v.x; t[r][c4 * 4 + 1] = v.y;
    t[r][c4 * 4 + 2] = v.z; t[r][c4 * 4 + 3] = v.w;
    __syncthreads();
    u16x4 o;
    o[0] = f2bf(t[c4 * 4 + 0][r]); o[1] = f2bf(t[c4 * 4 + 1][r]);
    o[2] = f2bf(t[c4 * 4 + 2][r]); o[3] = f2bf(t[c4 * 4 + 3][r]);
    *(u16x4*)(out + (size_t)(n0 + r) * 1024 + k0 + (c4 << 2)) = o;
}

// w1 (1024x4096) and w2 (4096x1024) in one launch: grid (128, 32, 2)
__global__ __launch_bounds__(256) void transpose_cvt2(const float* __restrict__ w1, const float* __restrict__ w2,
                                                      u16* __restrict__ o1, u16* __restrict__ o2) {
    __shared__ float t[32][33];
    const int zz = blockIdx.z;
    const float* in = zz ? w2 : w1;
    u16* out = zz ? o2 : o1;
    const int K = zz ? 4096 : 1024, N = zz ? 1024 : 4096;
    int k0, n0;
    if (zz) { k0 = blockIdx.x << 5; n0 = blockIdx.y << 5; }
    else    { n0 = blockIdx.x << 5; k0 = blockIdx.y << 5; }
    int r = threadIdx.x >> 3, c4 = threadIdx.x & 7;
    float4 v = *(const float4*)(in + (size_t)(k0 + r) * N + n0 + (c4 << 2));
    t[r][c4 * 4 + 0] = v.x; t[r][c4 * 4 + 1] = v.y;
    t[r][c4 * 4 + 2] = v.z; t[r][c4 * 4 + 3] = v.w;
    __syncthreads();
    u16x4 o;
    o[0] = f2bf(t[c4 * 4 + 0][r]); o[1] = f2bf(t[c4 * 4 + 1][r]);
    o[2] = f2bf(t[c4 * 4 + 2][r]); o[3] = f2bf(t[c4 * 4 + 3][r]);
    *(u16x4*)(out + (size_t)(n0 + r) * K + k0 + (c4 << 2)) = o;
}

// ---------------- prep: rope table + qkv bias concat + float mask (one launch, grid 256x256)
__global__ void prep_kernel(const float* __restrict__ bq, const float* __restrict__ bk,
                            const float* __restrict__ bv, float* __restrict__ bqkv,
                            const int* __restrict__ mask, float* __restrict__ maskf,
                            float* __restrict__ cost, float* __restrict__ sint) {
    int idx = blockIdx.x * 256 + threadIdx.x;  // 65536 = 2048 * 32
    int s = idx >> 5, f = idx & 31;
    float inv = powf(10000.0f, -((float)(2 * f)) / 64.0f);
    float a = (float)s * inv;
    cost[idx] = cosf(a);
    sint[idx] = sinf(a);
    if (idx < 3072) {
        float v = (idx < 1024) ? bq[idx] : (idx < 2048 ? bk[idx - 1024] : bv[idx - 2048]);
        bqkv[idx] = v;
    }
    if (idx < 4096) maskf[idx] = (float)mask[idx];
}

// ---------------- LayerNorm: 1 block / row of 1024, output bf16
__global__ __launch_bounds__(256) void ln_kernel(const float* __restrict__ x,
                                                 const float* __restrict__ gam,
                                                 const float* __restrict__ bet,
                                                 u16* __restrict__ out) {
    int row = blockIdx.x, tid = threadIdx.x;
    float4 v = *((const float4*)(x + (size_t)row * 1024) + tid);
    float s = v.x + v.y + v.z + v.w;
    float sq = v.x * v.x + v.y * v.y + v.z * v.z + v.w * v.w;
    #pragma unroll
    for (int off = 32; off >= 1; off >>= 1) {
        s += __shfl_xor(s, off);
        sq += __shfl_xor(sq, off);
    }
    __shared__ float red[8];
    int wid = tid >> 6, lane = tid & 63;
    if (lane == 0) { red[wid] = s; red[wid + 4] = sq; }
    __syncthreads();
    float ts = red[0] + red[1] + red[2] + red[3];
    float tq = red[4] + red[5] + red[6] + red[7];
    float mean = ts * (1.0f / 1024.0f);
    float var = tq * (1.0f / 1024.0f) - mean * mean;
    float rstd = rsqrtf(var + 1e-5f);
    float4 g = ((const float4*)gam)[tid];
    float4 b = ((const float4*)bet)[tid];
    u16x4 o;
    o[0] = f2bfn((v.x - mean) * rstd * g.x + b.x);
    o[1] = f2bfn((v.y - mean) * rstd * g.y + b.y);
    o[2] = f2bfn((v.z - mean) * rstd * g.z + b.z);
    o[3] = f2bfn((v.w - mean) * rstd * g.w + b.w);
    *(u16x4*)(out + (size_t)row * 1024 + (tid << 2)) = o;
}

// ---------------- LN2 fused with wo split-K merge: x2 += bf16 partial; xn = LN(x2)
__global__ __launch_bounds__(256) void ln_fuse(float* __restrict__ x2, const u16* __restrict__ part,
                                               const float* __restrict__ gam, const float* __restrict__ bet,
                                               u16* __restrict__ out) {
    int row = blockIdx.x, tid = threadIdx.x;
    float4 v = *((const float4*)(x2 + (size_t)row * 1024) + tid);
    u16x4 pv = *(const u16x4*)(part + (size_t)row * 1024 + (tid << 2));
    v.x += bf2f(pv[0]); v.y += bf2f(pv[1]); v.z += bf2f(pv[2]); v.w += bf2f(pv[3]);
    *((float4*)(x2 + (size_t)row * 1024) + tid) = v;   // residual base for FFN2
    float s = v.x + v.y + v.z + v.w;
    float sq = v.x * v.x + v.y * v.y + v.z * v.z + v.w * v.w;
    #pragma unroll
    for (int off = 32; off >= 1; off >>= 1) {
        s += __shfl_xor(s, off);
        sq += __shfl_xor(sq, off);
    }
    __shared__ float red[8];
    int wid = tid >> 6, lane = tid & 63;
    if (lane == 0) { red[wid] = s; red[wid + 4] = sq; }
    __syncthreads();
    float ts = red[0] + red[1] + red[2] + red[3];
    float tq = red[4] + red[5] + red[6] + red[7];
    float mean = ts * (1.0f / 1024.0f);
    float var = tq * (1.0f / 1024.0f) - mean * mean;
    float rstd = rsqrtf(var + 1e-5f);
    float4 g = ((const float4*)gam)[tid];
    float4 b = ((const float4*)bet)[tid];
    u16x4 o;
    o[0] = f2bfn((v.x - mean) * rstd * g.x + b.x);
    o[1] = f2bfn((v.y - mean) * rstd * g.y + b.y);
    o[2] = f2bfn((v.z - mean) * rstd * g.z + b.z);
    o[3] = f2bfn((v.w - mean) * rstd * g.w + b.w);
    *(u16x4*)(out + (size_t)row * 1024 + (tid << 2)) = o;
}

// ---------------- gemm256: 256x256 tile, BK=64, 8 waves (2Mx4N), phased schedule (T1+T2+T3+T4+T5)
// EPI 0: out bf16 = acc+bias      EPI 2: out bf16 = gelu(acc+bias)
template <int EPI>
__global__ __launch_bounds__(512, 2) void gemm256(const u16* __restrict__ A, const u16* __restrict__ Bt,
                                                  const float* __restrict__ bias,
                                                  u16* __restrict__ outb, int M, int N, int K) {
    __shared__ __align__(16) u16 lds[65536];   // 128 KB
    const int tid = threadIdx.x;
    const int lane = tid & 63, wid = tid >> 6;
    const int cl = lane & 15, g4 = lane >> 4;
    const int wr = wid >> 2, wc = wid & 3;     // 2 x 4 wave grid
    const int gx = gridDim.x;
    const int lid = blockIdx.y * gx + blockIdx.x;
    const int per8 = (gx * gridDim.y) >> 3;
    const int newlin = (lid & 7) * per8 + (lid >> 3);
    const int m0 = (newlin / gx) << 8;
    const int n0 = (newlin % gx) << 8;
    const int NT = K >> 6;
    f32x4 acc[8][4] = {};
    const int r0 = tid >> 3;          const int gc0 = (tid & 7) ^ (r0 & 7);
    const int r1 = (tid + 512) >> 3;  const int gc1 = (tid & 7) ^ (r1 & 7);
    const int wub = wid << 10;        // wave-uniform LDS byte base

    auto stageHalf = [&](int buf, int mat, int h, int kt) {
        const u16* src = mat ? Bt : A;
        const int base0 = mat ? n0 : m0;
        char* d = (char*)lds + buf * 65536 + mat * 32768 + h * 16384 + wub;
        gl_lds16(src + (size_t)(base0 + h * 128 + r0) * K + (kt << 6) + (gc0 << 3), d);
        gl_lds16(src + (size_t)(base0 + h * 128 + r1) * K + (kt << 6) + (gc1 << 3), d + 8192);
    };

    stageHalf(0, 0, 0, 0); stageHalf(0, 0, 1, 0);
    stageHalf(0, 1, 0, 0); stageHalf(0, 1, 1, 0);
    asm volatile("s_waitcnt vmcnt(0)" ::: "memory");
    __builtin_amdgcn_s_barrier();

    for (int t = 0; t < NT; ++t) {
        const int buf = t & 1, nbuf = buf ^ 1;
        const bool more = (t + 1 < NT);
        const int abase = buf * 65536 + wr * 16384;
        const int bbase = buf * 65536 + 32768 + (wc >> 1) * 16384;
        bf16x8 bfr[4][2];
        #pragma unroll
        for (int q = 0; q < 4; ++q) {
            bf16x8 afr[2][2];
            #pragma unroll
            for (int di = 0; di < 2; ++di)
                #pragma unroll
                for (int ks = 0; ks < 2; ++ks) {
                    int row = q * 32 + di * 16 + cl;
                    int gr = ks * 4 + g4;
                    afr[di][ks] = *(const bf16x8*)((char*)lds + abase + (((row << 3) + (gr ^ (row & 7))) << 4));
                }
            if (q == 0) {
                #pragma unroll
                for (int j = 0; j < 4; ++j)
                    #pragma unroll
                    for (int ks = 0; ks < 2; ++ks) {
                        int row = ((wc & 1) << 6) + j * 16 + cl;
                        int gr = ks * 4 + g4;
                        bfr[j][ks] = *(const bf16x8*)((char*)lds + bbase + (((row << 3) + (gr ^ (row & 7))) << 4));
                    }
            }
            if (more) stageHalf(nbuf, q >> 1, q & 1, t + 1);   // A-h0, A-h1, B-h0, B-h1
            __builtin_amdgcn_s_barrier();
            asm volatile("s_waitcnt lgkmcnt(0)" ::: "memory");
            __builtin_amdgcn_sched_barrier(0);
            __builtin_amdgcn_s_setprio(1);
            #pragma unroll
            for (int di = 0; di < 2; ++di)
                #pragma unroll
                for (int j = 0; j < 4; ++j)
                    #pragma unroll
                    for (int ks = 0; ks < 2; ++ks)
                        acc[q * 2 + di][j] = __builtin_amdgcn_mfma_f32_16x16x32_bf16(
                            afr[di][ks], bfr[j][ks], acc[q * 2 + di][j], 0, 0, 0);
            __builtin_amdgcn_s_setprio(0);
            if (q == 3 && more) asm volatile("s_waitcnt vmcnt(0)" ::: "memory");
            __builtin_amdgcn_s_barrier();
            if (q == 3) __builtin_amdgcn_sched_barrier(0);
        }
    }
    #pragma unroll
    for (int i = 0; i < 8; ++i)
        #pragma unroll
        for (int j = 0; j < 4; ++j) {
            int row = m0 + wr * 128 + i * 16 + g4 * 4;
            int col = n0 + wc * 64 + j * 16 + cl;
            float bc = bias[col];
            #pragma unroll
            for (int rr = 0; rr < 4; ++rr) {
                float v = acc[i][j][rr] + bc;
                size_t idx = (size_t)(row + rr) * N + col;
                if constexpr (EPI == 0) {
                    outb[idx] = f2bfn(v);
                } else {
                    float tg = 0.7978845608f * (v + 0.044715f * v * v * v);
                    outb[idx] = f2bfn(v / (1.0f + exp2f(tg * -2.88539008f)));  // v*sigmoid(2t)
                }
            }
        }
}

// ---------------- gemm256r: gemm256 with split-K via grid.z (FFN2).
// z == 0: out f32 = acc + bias + res.   z > 0: bf16 raw partial at poutb + (z-1)*M*N.
__global__ __launch_bounds__(512, 2) void gemm256r(const u16* __restrict__ A, const u16* __restrict__ Bt,
                                                   const float* __restrict__ bias,
                                                   const float* __restrict__ res,
                                                   float* __restrict__ outf, u16* __restrict__ poutb,
                                                   int M, int N, int K) {
    __shared__ __align__(16) u16 lds[65536];   // 128 KB
    const int tid = threadIdx.x;
    const int lane = tid & 63, wid = tid >> 6;
    const int cl = lane & 15, g4 = lane >> 4;
    const int wr = wid >> 2, wc = wid & 3;     // 2 x 4 wave grid
    const int gx = gridDim.x;
    const int lid = blockIdx.y * gx + blockIdx.x;
    const int per8 = (gx * gridDim.y) >> 3;
    const int newlin = (lid & 7) * per8 + (lid >> 3);
    const int m0 = (newlin / gx) << 8;
    const int n0 = (newlin % gx) << 8;
    const int kchunk = K / gridDim.z;
    const int kbase = blockIdx.z * kchunk;
    const int NT = kchunk >> 6;
    f32x4 acc[8][4] = {};
    const int r0 = tid >> 3;          const int gc0 = (tid & 7) ^ (r0 & 7);
    const int r1 = (tid + 512) >> 3;  const int gc1 = (tid & 7) ^ (r1 & 7);
    const int wub = wid << 10;

    auto stageHalf = [&](int buf, int mat, int h, int kt) {
        const u16* src = mat ? Bt : A;
        const int base0 = mat ? n0 : m0;
        char* d = (char*)lds + buf * 65536 + mat * 32768 + h * 16384 + wub;
        gl_lds16(src + (size_t)(base0 + h * 128 + r0) * K + kbase + (kt << 6) + (gc0 << 3), d);
        gl_lds16(src + (size_t)(base0 + h * 128 + r1) * K + kbase + (kt << 6) + (gc1 << 3), d + 8192);
    };

    stageHalf(0, 0, 0, 0); stageHalf(0, 0, 1, 0);
    stageHalf(0, 1, 0, 0); stageHalf(0, 1, 1, 0);
    asm volatile("s_waitcnt vmcnt(0)" ::: "memory");
    __builtin_amdgcn_s_barrier();

    for (int t = 0; t < NT; ++t) {
        const int buf = t & 1, nbuf = buf ^ 1;
        const bool more = (t + 1 < NT);
        const int abase = buf * 65536 + wr * 16384;
        const int bbase = buf * 65536 + 32768 + (wc >> 1) * 16384;
        bf16x8 bfr[4][2];
        #pragma unroll
        for (int q = 0; q < 4; ++q) {
            bf16x8 afr[2][2];
            #pragma unroll
            for (int di = 0; di < 2; ++di)
                #pragma unroll
                for (int ks = 0; ks < 2; ++ks) {
                    int row = q * 32 + di * 16 + cl;
                    int gr = ks * 4 + g4;
                    afr[di][ks] = *(const bf16x8*)((char*)lds + abase + (((row << 3) + (gr ^ (row & 7))) << 4));
                }
            if (q == 0) {
                #pragma unroll
                for (int j = 0; j < 4; ++j)
                    #pragma unroll
                    for (int ks = 0; ks < 2; ++ks) {
                        int row = ((wc & 1) << 6) + j * 16 + cl;
                        int gr = ks * 4 + g4;
                        bfr[j][ks] = *(const bf16x8*)((char*)lds + bbase + (((row << 3) + (gr ^ (row & 7))) << 4));
                    }
            }
            if (more) stageHalf(nbuf, q >> 1, q & 1, t + 1);
            __builtin_amdgcn_s_barrier();
            asm volatile("s_waitcnt lgkmcnt(0)" ::: "memory");
            __builtin_amdgcn_sched_barrier(0);
            __builtin_amdgcn_s_setprio(1);
            #pragma unroll
            for (int di = 0; di < 2; ++di)
                #pragma unroll
                for (int j = 0; j < 4; ++j)
                    #pragma unroll
                    for (int ks = 0; ks < 2; ++ks)
                        acc[q * 2 + di][j] = __builtin_amdgcn_mfma_f32_16x16x32_bf16(
                            afr[di][ks], bfr[j][ks], acc[q * 2 + di][j], 0, 0, 0);
            __builtin_amdgcn_s_setprio(0);
            if (q == 3 && more) asm volatile("s_waitcnt vmcnt(0)" ::: "memory");
            __builtin_amdgcn_s_barrier();
            if (q == 3) __builtin_amdgcn_sched_barrier(0);
        }
    }
    if (blockIdx.z == 0) {
        #pragma unroll
        for (int i = 0; i < 8; ++i)
            #pragma unroll
            for (int j = 0; j < 4; ++j) {
                int row = m0 + wr * 128 + i * 16 + g4 * 4;
                int col = n0 + wc * 64 + j * 16 + cl;
                float bc = bias[col];
                #pragma unroll
                for (int rr = 0; rr < 4; ++rr) {
                    size_t idx = (size_t)(row + rr) * N + col;
                    outf[idx] = acc[i][j][rr] + bc + res[idx];
                }
            }
    } else {
        const size_t pbase = (size_t)(blockIdx.z - 1) * ((size_t)M * N);
        #pragma unroll
        for (int i = 0; i < 8; ++i)
            #pragma unroll
            for (int j = 0; j < 4; ++j) {
                int row = m0 + wr * 128 + i * 16 + g4 * 4;
                int col = n0 + wc * 64 + j * 16 + cl;
                #pragma unroll
                for (int rr = 0; rr < 4; ++rr)
                    poutb[pbase + (size_t)(row + rr) * N + col] = f2bfn(acc[i][j][rr]);
            }
    }
}

// ---------------- GEMM 128^2 (m97 + T1 + T4 + granule permute): used for wo
template <int EPI>
__global__ __launch_bounds__(256) void gemm_bt(const u16* __restrict__ A, const u16* __restrict__ Bt,
                                               const float* __restrict__ bias,
                                               const float* __restrict__ res,
                                               u16* __restrict__ outb, float* __restrict__ outf,
                                               u16* __restrict__ poutb,
                                               int M, int N, int K) {
    __shared__ __align__(16) u16 As[3][4096];
    __shared__ __align__(16) u16 Bs[3][4096];
    const int tid = threadIdx.x;
    const int lane = tid & 63, wid = tid >> 6;
    const int g = lane >> 4, cl = lane & 15;
    const int wr = wid >> 1, wc = wid & 1;
    const int gx = gridDim.x;
    const int lid = blockIdx.y * gx + blockIdx.x;
    const int per8 = (gx * gridDim.y) >> 3;
    const int newlin = (lid & 7) * per8 + (lid >> 3);
    const int m0 = (newlin / gx) << 7;
    const int n0 = (newlin % gx) << 7;
    const int kchunk = K / gridDim.z;
    const int kbase = blockIdx.z * kchunk;
    const int NT = kchunk >> 5;
    f32x4 acc[4][4] = {};
    const int grow = tid >> 2;
    const int gcol = (tid & 3) ^ ((tid >> 3) & 3);

    auto stage = [&](int buf, int kt) {
        const int ko = kbase + (kt << 5);
        gl_lds16(A + (size_t)(m0 + grow) * K + ko + (gcol << 3),       &As[buf][wid << 9]);
        gl_lds16(A + (size_t)(m0 + grow + 64) * K + ko + (gcol << 3),  &As[buf][(wid << 9) + 2048]);
        gl_lds16(Bt + (size_t)(n0 + grow) * K + ko + (gcol << 3),      &Bs[buf][wid << 9]);
        gl_lds16(Bt + (size_t)(n0 + grow + 64) * K + ko + (gcol << 3), &Bs[buf][(wid << 9) + 2048]);
    };

    stage(0, 0);
    stage(1, 1);
    for (int kt = 0; kt < NT; ++kt) {
        if (kt + 1 < NT) asm volatile("s_waitcnt vmcnt(4)" ::: "memory");
        else             asm volatile("s_waitcnt vmcnt(0)" ::: "memory");
        __builtin_amdgcn_s_barrier();
        __builtin_amdgcn_sched_barrier(0);
        if (kt + 2 < NT) stage((kt + 2) % 3, kt + 2);
        const int cb = kt % 3;
        bf16x8 a[4], b[4];
        #pragma unroll
        for (int i = 0; i < 4; ++i) {
            int row = (wr << 6) + (i << 4) + cl;
            a[i] = *(const bf16x8*)&As[cb][((row << 2) + (g ^ ((row >> 1) & 3))) << 3];
        }
        #pragma unroll
        for (int j = 0; j < 4; ++j) {
            int row = (wc << 6) + (j << 4) + cl;
            b[j] = *(const bf16x8*)&Bs[cb][((row << 2) + (g ^ ((row >> 1) & 3))) << 3];
        }
        __builtin_amdgcn_s_setprio(1);
        #pragma unroll
        for (int i = 0; i < 4; ++i)
            #pragma unroll
            for (int j = 0; j < 4; ++j)
                acc[i][j] = __builtin_amdgcn_mfma_f32_16x16x32_bf16(a[i], b[j], acc[i][j], 0, 0, 0);
        __builtin_amdgcn_s_setprio(0);
    }
    if (blockIdx.z == 0) {
        #pragma unroll
        for (int i = 0; i < 4; ++i)
            #pragma unroll
            for (int j = 0; j < 4; ++j) {
                int row = m0 + (wr << 6) + (i << 4) + (g << 2);
                int col = n0 + (wc << 6) + (j << 4) + cl;
                float bc = bias[col];
                #pragma unroll
                for (int rr = 0; rr < 4; ++rr) {
                    float v = acc[i][j][rr] + bc;
                    size_t idx = (size_t)(row + rr) * N + col;
                    outf[idx] = v + res[idx];
                }
            }
    } else {
        const size_t pbase = (size_t)(blockIdx.z - 1) * ((size_t)M * N);
        #pragma unroll
        for (int i = 0; i < 4; ++i)
            #pragma unroll
            for (int j = 0; j < 4; ++j) {
                int row = m0 + (wr << 6) + (i << 4) + (g << 2);
                int col = n0 + (wc << 6) + (j << 4) + cl;
                #pragma unroll
                for (int rr = 0; rr < 4; ++rr)
                    poutb[pbase + (size_t)(row + rr) * N + col] = f2bfn(acc[i][j][rr]);
            }
    }
}

// ---------------- split-K reduce: out += sum of bf16 partials (each 4096*1024 elements)
__global__ __launch_bounds__(256) void reduce_addb(float* __restrict__ out, const u16* __restrict__ p,
                                                   int nparts) {
    int i = blockIdx.x * 256 + threadIdx.x;   // x4 elements
    float4 a = ((const float4*)out)[i];
    for (int j = 0; j < nparts; ++j) {
        u16x4 v = *(const u16x4*)(p + (size_t)j * 4194304 + ((size_t)i << 2));
        a.x += bf2f(v[0]); a.y += bf2f(v[1]); a.z += bf2f(v[2]); a.w += bf2f(v[3]);
    }
    ((float4*)out)[i] = a;
}

// ---------------- RoPE for q,k: qkv[4096][3072] -> qr/kr [BH][S][64]
// q pre-scaled by 0.125 * log2(e) so attention uses exp2 directly
__global__ __launch_bounds__(256) void rope_qk(const u16* __restrict__ qkv,
                                               const float* __restrict__ cost,
                                               const float* __restrict__ sint,
                                               u16* __restrict__ qr, u16* __restrict__ kr) {
    int tid = threadIdx.x;
    int rowid = (blockIdx.x << 4) + (tid >> 4);  // bh*2048+s over [0,65536)
    int j = tid & 15;
    int half = j >> 3, jj = j & 7;
    int b = rowid >> 15;
    int h = (rowid >> 11) & 15;
    int s = rowid & 2047;
    size_t qbase = (size_t)((b << 11) + s) * 3072 + (h << 6);
    float cf[4], sf_[4];
    {
        float4 c = *(const float4*)(cost + (s << 5) + (jj << 2));
        float4 sn = *(const float4*)(sint + (s << 5) + (jj << 2));
        cf[0] = c.x; cf[1] = c.y; cf[2] = c.z; cf[3] = c.w;
        sf_[0] = sn.x; sf_[1] = sn.y; sf_[2] = sn.z; sf_[3] = sn.w;
    }
    size_t obase = (size_t)rowid * 64 + (half << 5) + (jj << 2);
    {
        u16x8 v = *(const u16x8*)(qkv + qbase + (jj << 3));
        u16x4 o;
        #pragma unroll
        for (int m2 = 0; m2 < 4; ++m2) {
            float e = bf2f(v[2 * m2]), od = bf2f(v[2 * m2 + 1]);
            float val = (half == 0) ? (e * cf[m2] - od * sf_[m2]) : (e * sf_[m2] + od * cf[m2]);
            o[m2] = f2bfn(val * 0.1803368801f);  // 0.125 * log2(e)
        }
        *(u16x4*)(qr + obase) = o;
    }
    {
        u16x8 v = *(const u16x8*)(qkv + qbase + 1024 + (jj << 3));
        u16x4 o;
        #pragma unroll
        for (int m2 = 0; m2 < 4; ++m2) {
            float e = bf2f(v[2 * m2]), od = bf2f(v[2 * m2 + 1]);
            float val = (half == 0) ? (e * cf[m2] - od * sf_[m2]) : (e * sf_[m2] + od * cf[m2]);
            o[m2] = f2bfn(val);
        }
        *(u16x4*)(kr + obase) = o;
    }
}

// ---------------- V transpose: qkv v-part -> vt[BH][64 d][2048 s]
__global__ __launch_bounds__(256) void v_transpose(const u16* __restrict__ qkv,
                                                   u16* __restrict__ vt) {
    __shared__ __align__(16) u16 tl[64 * 80];
    int stile = blockIdx.x, bh = blockIdx.y;
    int b = bh >> 4, h = bh & 15;
    int tid = threadIdx.x;
    #pragma unroll
    for (int i = 0; i < 2; ++i) {
        int slot = tid + (i << 8);
        int srow = slot >> 3, c = slot & 7;
        u16x8 v = *(const u16x8*)(qkv + (size_t)((b << 11) + (stile << 6) + srow) * 3072 + 2048 + (h << 6) + (c << 3));
        *(u16x8*)(tl + srow * 80 + (c << 3)) = v;
    }
    __syncthreads();
    #pragma unroll
    for (int i = 0; i < 2; ++i) {
        int slot = tid + (i << 8);
        int drow = slot >> 3, c = slot & 7;
        u16x8 o;
        #pragma unroll
        for (int m2 = 0; m2 < 8; ++m2) o[m2] = tl[(c * 8 + m2) * 80 + drow];
        *(u16x8*)(vt + ((size_t)bh * 64 + drow) * 2048 + (stile << 6) + (c << 3)) = o;
    }
}

// ---------------- flash attention v8: NO K/V LDS staging — K/V are L2-resident (XCD head
// affinity), so MFMA fragments load directly from global (64B-coalesced per instruction).
// No barriers in the loop (only wave-private Ps). Triangle-paired blocks, swapped QK^T,
// float mask, cvt_pk P-pack.
__global__ __launch_bounds__(256) void attn_kernel(const u16* __restrict__ Q, const u16* __restrict__ Kd,
                                                   const u16* __restrict__ Vt, const float* __restrict__ maskf,
                                                   u16* __restrict__ ctx) {
    __shared__ __align__(16) u16 Ps[4096];
    const int tid = threadIdx.x, lane = tid & 63, w = tid >> 6;
    const int g = lane >> 4, cl = lane & 15;
    const int lid = blockIdx.y * 16 + blockIdx.x;   // grid (16,32) = 512 blocks
    const int xcd = lid & 7, slot = lid >> 3;       // slot in [0,64)
    const int bh = xcd * 4 + (slot >> 4);           // 4 heads per XCD (K/V L2-resident)
    const int pair = slot & 15;                     // 16 pair-blocks per head
    const int b = bh >> 4, h = bh & 15;
    const u16* Kb = Kd + (size_t)bh * 2048 * 64;
    const u16* Vb = Vt + (size_t)bh * 64 * 2048;
    bf16x8 onesb;
    #pragma unroll
    for (int i2 = 0; i2 < 8; ++i2) onesb[i2] = (__bf16)1.0f;
    // P write base: row = q = cl, 8B slot for (ct,g) at granule (ct*2+(g>>1)) ^ (cl&7)
    char* const pwb = (char*)Ps + w * 2048 + cl * 128 + ((g & 1) << 3);
    // V fragment row base (d-rows n*16+cl, 64B-coalesced across the 4 g-lanes)
    const u16* const vrow0 = Vb + (size_t)cl * 2048 + (g << 3);

    #pragma unroll
    for (int ci = 0; ci < 2; ++ci) {
        const int qb = (ci == 0) ? (31 - pair) : pair;  // heavy chunk first
        const size_t qoff = ((size_t)bh * 2048 + qb * 64 + w * 16 + cl) * 64;
        const bf16x8 qa0 = *(const bf16x8*)(Q + qoff + (g << 3));
        const bf16x8 qa1 = *(const bf16x8*)(Q + qoff + 32 + (g << 3));
        const int qrow = qb * 64 + w * 16 + cl;     // this lane's q row (S^T layout)
        f32x4 acc[4] = {};
        f32x4 lsum = {};

        for (int t = 0; t <= qb; ++t) {
            // K fragments direct from global (L2-hit): row = t*64 + ct*16 + cl, 16B at (ks*4+g)*8
            bf16x8 kf[4][2];
            #pragma unroll
            for (int ct = 0; ct < 4; ++ct)
                #pragma unroll
                for (int ks = 0; ks < 2; ++ks)
                    kf[ct][ks] = *(const bf16x8*)(Kb + ((size_t)(t * 64 + ct * 16 + cl)) * 64 + (((ks << 2) + g) << 3));
            // swapped QK^T: sf[ct][rr] = S[q = qrow][k = t*64 + ct*16 + g*4 + rr]
            f32x4 sf[4];
            __builtin_amdgcn_s_setprio(1);
            #pragma unroll
            for (int ct = 0; ct < 4; ++ct) {
                f32x4 s = {};
                s = __builtin_amdgcn_mfma_f32_16x16x32_bf16(kf[ct][0], qa0, s, 0, 0, 0);
                s = __builtin_amdgcn_mfma_f32_16x16x32_bf16(kf[ct][1], qa1, s, 0, 0, 0);
                sf[ct] = s;
            }
            __builtin_amdgcn_s_setprio(0);
            // p = exp2(s) * mask * causal; pack 4 consecutive k as 2 cvt_pk -> one 8B write
            const bool diag = (t == qb);
            #pragma unroll
            for (int ct = 0; ct < 4; ++ct) {
                const int kc0 = t * 64 + ct * 16 + (g << 2);
                const float4 mv = *(const float4*)(maskf + (b << 11) + kc0);
                float p0 = exp2f(sf[ct][0]) * mv.x;
                float p1 = exp2f(sf[ct][1]) * mv.y;
                float p2 = exp2f(sf[ct][2]) * mv.z;
                float p3 = exp2f(sf[ct][3]) * mv.w;
                if (diag) {
                    p0 = (kc0 + 0 <= qrow) ? p0 : 0.0f;
                    p1 = (kc0 + 1 <= qrow) ? p1 : 0.0f;
                    p2 = (kc0 + 2 <= qrow) ? p2 : 0.0f;
                    p3 = (kc0 + 3 <= qrow) ? p3 : 0.0f;
                }
                u32 lo, hi;
                asm("v_cvt_pk_bf16_f32 %0, %1, %2" : "=v"(lo) : "v"(p0), "v"(p1));
                asm("v_cvt_pk_bf16_f32 %0, %1, %2" : "=v"(hi) : "v"(p2), "v"(p3));
                uint2 pk; pk.x = lo; pk.y = hi;
                *(uint2*)(pwb + ((((ct << 1) + (g >> 1)) ^ (cl & 7)) << 4)) = pk;
            }
            // PV + row-sum (ones-MFMA); V fragments direct from global (L2-hit)
            __builtin_amdgcn_s_setprio(1);
            #pragma unroll
            for (int kc = 0; kc < 2; ++kc) {
                bf16x8 pa = *(const bf16x8*)((char*)Ps + w * 2048 + cl * 128 + (((kc * 4 + g) ^ (cl & 7)) << 4));
                lsum = __builtin_amdgcn_mfma_f32_16x16x32_bf16(pa, onesb, lsum, 0, 0, 0);
                #pragma unroll
                for (int n = 0; n < 4; ++n) {
                    bf16x8 vb = *(const bf16x8*)(vrow0 + (size_t)(n << 4) * 2048 + t * 64 + (kc << 5));
                    acc[n] = __builtin_amdgcn_mfma_f32_16x16x32_bf16(pa, vb, acc[n], 0, 0, 0);
                }
            }
            __builtin_amdgcn_s_setprio(0);
        }
        // output: ctx[token][h*64 + d]
        #pragma unroll
        for (int n = 0; n < 4; ++n)
            #pragma unroll
            for (int rr = 0; rr < 4; ++rr) {
                int token = (b << 11) + qb * 64 + w * 16 + g * 4 + rr;
                int col = (h << 6) + n * 16 + cl;
                ctx[(size_t)token * 1024 + col] = f2bfn(acc[n][rr] / lsum[rr]);
            }
    }
}

extern "C" void kernel_launch(void* const* d_in, const int* in_sizes, int n_in,
                              void* d_out, int out_size, void* d_ws, size_t ws_size,
                              hipStream_t stream) {
    const float* x   = (const float*)d_in[0];
    const int* mask  = (const int*)d_in[1];
    const float* wq  = (const float*)d_in[2];
    const float* bq  = (const float*)d_in[3];
    const float* wk  = (const float*)d_in[4];
    const float* bk  = (const float*)d_in[5];
    const float* wv  = (const float*)d_in[6];
    const float* bv  = (const float*)d_in[7];
    const float* wo  = (const float*)d_in[8];
    const float* bo  = (const float*)d_in[9];
    const float* w1  = (const float*)d_in[10];
    const float* b1  = (const float*)d_in[11];
    const float* w2  = (const float*)d_in[12];
    const float* b2  = (const float*)d_in[13];
    const float* g1  = (const float*)d_in[14];
    const float* be1 = (const float*)d_in[15];
    const float* g2  = (const float*)d_in[16];
    const float* be2 = (const float*)d_in[17];
    float* out = (float*)d_out;
    char* ws = (char*)d_ws;

    // ws map (109.59 MB total, overlays noted):
    u16* wqkvT  = (u16*)(ws + 0);            //  6 MB, whole call
    u16* woT    = (u16*)(ws + 6291456);      //  2 MB
    u16* w1T    = (u16*)(ws + 8388608);      //  8 MB
    u16* w2T    = (u16*)(ws + 16777216);     //  8 MB
    float* bqkv = (float*)(ws + 25165824);   // 12 KB
    float* cost = (float*)(ws + 25178112);   // 256 KB
    float* sint = (float*)(ws + 25440256);   // 256 KB
    u16* xn     = (u16*)(ws + 25702400);     //  8 MB (LN1 out; reused for LN2 out)
    float* x2   = (float*)(ws + 34091008);   // 16 MB (residual-2 base; first written by wo-gemm)
    float* maskf= (float*)(ws + 34091008);   // 16 KB overlay on x2 head (dead once wo-gemm writes x2)
    u16* qkv    = (u16*)(ws + 50868224);     // 24 MB (dead after v_transpose)
    u16* ffh    = (u16*)(ws + 50868224);     // 32 MB overlay on qkv+qr; spans to 84422656
    u16* qr     = (u16*)(ws + 76034048);     //  8 MB (dead after attn)
    u16* kr     = (u16*)(ws + 84422656);     //  8 MB (dead after attn)
    u16* vt     = (u16*)(ws + 92811264);     //  8 MB (dead after attn)
    u16* ctx    = (u16*)(ws + 101199872);    //  8 MB (dead after wo-gemm)
    // bf16 split-K partials: 3 x 8 MB on kr+vt+ctx. DISJOINT from ffh (ends 84422656).
    u16* partb  = (u16*)(ws + 84422656);

    transpose_cvt4<<<dim3(32, 32, 4), 256, 0, stream>>>(wq, wk, wv, wo,
                                                        wqkvT, wqkvT + 1024 * 1024, wqkvT + 2048 * 1024, woT);
    transpose_cvt2<<<dim3(128, 32, 2), 256, 0, stream>>>(w1, w2, w1T, w2T);
    prep_kernel<<<256, 256, 0, stream>>>(bq, bk, bv, bqkv, mask, maskf, cost, sint);

    ln_kernel<<<4096, 256, 0, stream>>>(x, g1, be1, xn);
    gemm256<0><<<dim3(12, 16), 512, 0, stream>>>(xn, wqkvT, bqkv, qkv, 4096, 3072, 1024);
    rope_qk<<<4096, 256, 0, stream>>>(qkv, cost, sint, qr, kr);
    v_transpose<<<dim3(32, 32), 256, 0, stream>>>(qkv, vt);
    attn_kernel<<<dim3(16, 32), 256, 0, stream>>>(qr, kr, vt, maskf, ctx);
    gemm_bt<1><<<dim3(8, 32, 2), 256, 0, stream>>>(ctx, woT, bo, x, nullptr, x2, partb, 4096, 1024, 1024);
    ln_fuse<<<4096, 256, 0, stream>>>(x2, partb, g2, be2, xn);
    gemm256<2><<<dim3(16, 16), 512, 0, stream>>>(xn, w1T, b1, ffh, 4096, 4096, 1024);
    gemm256r<<<dim3(4, 16, 4), 512, 0, stream>>>(ffh, w2T, b2, x2, out, partb, 4096, 1024, 4096);
    reduce_addb<<<4096, 256, 0, stream>>>(out, partb, 3);
}

// Round 16
// 241.167 us; speedup vs baseline: 1.3393x; 1.3393x over previous
//
#include <hip/hip_runtime.h>

typedef unsigned short u16;
typedef unsigned int u32;
typedef __attribute__((ext_vector_type(8))) u16 u16x8;
typedef __attribute__((ext_vector_type(4))) u16 u16x4;
typedef __attribute__((ext_vector_type(8))) __bf16 bf16x8;
typedef __attribute__((ext_vector_type(4))) float f32x4;

static __device__ __forceinline__ float bf2f(u16 u) {
    union { u32 i; float f; } v; v.i = ((u32)u) << 16; return v.f;
}
static __device__ __forceinline__ u16 f2bf(float f) {   // manual RNE (cold paths)
    union { float f; u32 i; } v; v.f = f;
    u32 r = v.i + 0x7fffu + ((v.i >> 16) & 1u);
    return (u16)(r >> 16);
}
static __device__ __forceinline__ u16 f2bfn(float f) {  // native cvt (hot paths)
    __bf16 h = (__bf16)f;
    return *(u16*)&h;
}
// async global -> LDS, 16B per lane; ldst must be wave-uniform (HW adds lane*16)
static __device__ __forceinline__ void gl_lds16(const void* gsrc, void* ldst) {
    __builtin_amdgcn_global_load_lds((const __attribute__((address_space(1))) void*)gsrc,
                                     (__attribute__((address_space(3))) void*)ldst, 16, 0, 0);
}

// ---------------- weight transpose + fp32->bf16 convert: out[n][k] = in[k][n]
// batched 1024x1024 variant: z selects (wq,wk,wv,wo)
__global__ __launch_bounds__(256) void transpose_cvt4(const float* __restrict__ w0, const float* __restrict__ w1,
                                                      const float* __restrict__ w2, const float* __restrict__ w3,
                                                      u16* __restrict__ o0, u16* __restrict__ o1,
                                                      u16* __restrict__ o2, u16* __restrict__ o3) {
    __shared__ float t[32][33];
    const float* in; u16* out;
    switch (blockIdx.z) {
        case 0:  in = w0; out = o0; break;
        case 1:  in = w1; out = o1; break;
        case 2:  in = w2; out = o2; break;
        default: in = w3; out = o3; break;
    }
    int k0 = blockIdx.y << 5, n0 = blockIdx.x << 5;
    int r = threadIdx.x >> 3, c4 = threadIdx.x & 7;
    float4 v = *(const float4*)(in + (size_t)(k0 + r) * 1024 + n0 + (c4 << 2));
    t[r][c4 * 4 + 0] = v.x; t[r][c4 * 4 + 1] = v.y;
    t[r][c4 * 4 + 2] = v.z; t[r][c4 * 4 + 3] = v.w;
    __syncthreads();
    u16x4 o;
    o[0] = f2bf(t[c4 * 4 + 0][r]); o[1] = f2bf(t[c4 * 4 + 1][r]);
    o[2] = f2bf(t[c4 * 4 + 2][r]); o[3] = f2bf(t[c4 * 4 + 3][r]);
    *(u16x4*)(out + (size_t)(n0 + r) * 1024 + k0 + (c4 << 2)) = o;
}

// w1 (1024x4096) and w2 (4096x1024) in one launch: grid (128, 32, 2)
__global__ __launch_bounds__(256) void transpose_cvt2(const float* __restrict__ w1, const float* __restrict__ w2,
                                                      u16* __restrict__ o1, u16* __restrict__ o2) {
    __shared__ float t[32][33];
    const int zz = blockIdx.z;
    const float* in = zz ? w2 : w1;
    u16* out = zz ? o2 : o1;
    const int K = zz ? 4096 : 1024, N = zz ? 1024 : 4096;
    int k0, n0;
    if (zz) { k0 = blockIdx.x << 5; n0 = blockIdx.y << 5; }
    else    { n0 = blockIdx.x << 5; k0 = blockIdx.y << 5; }
    int r = threadIdx.x >> 3, c4 = threadIdx.x & 7;
    float4 v = *(const float4*)(in + (size_t)(k0 + r) * N + n0 + (c4 << 2));
    t[r][c4 * 4 + 0] = v.x; t[r][c4 * 4 + 1] = v.y;
    t[r][c4 * 4 + 2] = v.z; t[r][c4 * 4 + 3] = v.w;
    __syncthreads();
    u16x4 o;
    o[0] = f2bf(t[c4 * 4 + 0][r]); o[1] = f2bf(t[c4 * 4 + 1][r]);
    o[2] = f2bf(t[c4 * 4 + 2][r]); o[3] = f2bf(t[c4 * 4 + 3][r]);
    *(u16x4*)(out + (size_t)(n0 + r) * K + k0 + (c4 << 2)) = o;
}

// ---------------- prep: rope table + qkv bias concat + float mask (one launch, grid 256x256)
__global__ void prep_kernel(const float* __restrict__ bq, const float* __restrict__ bk,
                            const float* __restrict__ bv, float* __restrict__ bqkv,
                            const int* __restrict__ mask, float* __restrict__ maskf,
                            float* __restrict__ cost, float* __restrict__ sint) {
    int idx = blockIdx.x * 256 + threadIdx.x;  // 65536 = 2048 * 32
    int s = idx >> 5, f = idx & 31;
    float inv = powf(10000.0f, -((float)(2 * f)) / 64.0f);
    float a = (float)s * inv;
    cost[idx] = cosf(a);
    sint[idx] = sinf(a);
    if (idx < 3072) {
        float v = (idx < 1024) ? bq[idx] : (idx < 2048 ? bk[idx - 1024] : bv[idx - 2048]);
        bqkv[idx] = v;
    }
    if (idx < 4096) maskf[idx] = (float)mask[idx];
}

// ---------------- LayerNorm: 1 block / row of 1024, output bf16
__global__ __launch_bounds__(256) void ln_kernel(const float* __restrict__ x,
                                                 const float* __restrict__ gam,
                                                 const float* __restrict__ bet,
                                                 u16* __restrict__ out) {
    int row = blockIdx.x, tid = threadIdx.x;
    float4 v = *((const float4*)(x + (size_t)row * 1024) + tid);
    float s = v.x + v.y + v.z + v.w;
    float sq = v.x * v.x + v.y * v.y + v.z * v.z + v.w * v.w;
    #pragma unroll
    for (int off = 32; off >= 1; off >>= 1) {
        s += __shfl_xor(s, off);
        sq += __shfl_xor(sq, off);
    }
    __shared__ float red[8];
    int wid = tid >> 6, lane = tid & 63;
    if (lane == 0) { red[wid] = s; red[wid + 4] = sq; }
    __syncthreads();
    float ts = red[0] + red[1] + red[2] + red[3];
    float tq = red[4] + red[5] + red[6] + red[7];
    float mean = ts * (1.0f / 1024.0f);
    float var = tq * (1.0f / 1024.0f) - mean * mean;
    float rstd = rsqrtf(var + 1e-5f);
    float4 g = ((const float4*)gam)[tid];
    float4 b = ((const float4*)bet)[tid];
    u16x4 o;
    o[0] = f2bfn((v.x - mean) * rstd * g.x + b.x);
    o[1] = f2bfn((v.y - mean) * rstd * g.y + b.y);
    o[2] = f2bfn((v.z - mean) * rstd * g.z + b.z);
    o[3] = f2bfn((v.w - mean) * rstd * g.w + b.w);
    *(u16x4*)(out + (size_t)row * 1024 + (tid << 2)) = o;
}

// ---------------- LN2 fused with wo split-K merge: x2 += bf16 partial; xn = LN(x2)
__global__ __launch_bounds__(256) void ln_fuse(float* __restrict__ x2, const u16* __restrict__ part,
                                               const float* __restrict__ gam, const float* __restrict__ bet,
                                               u16* __restrict__ out) {
    int row = blockIdx.x, tid = threadIdx.x;
    float4 v = *((const float4*)(x2 + (size_t)row * 1024) + tid);
    u16x4 pv = *(const u16x4*)(part + (size_t)row * 1024 + (tid << 2));
    v.x += bf2f(pv[0]); v.y += bf2f(pv[1]); v.z += bf2f(pv[2]); v.w += bf2f(pv[3]);
    *((float4*)(x2 + (size_t)row * 1024) + tid) = v;   // residual base for FFN2
    float s = v.x + v.y + v.z + v.w;
    float sq = v.x * v.x + v.y * v.y + v.z * v.z + v.w * v.w;
    #pragma unroll
    for (int off = 32; off >= 1; off >>= 1) {
        s += __shfl_xor(s, off);
        sq += __shfl_xor(sq, off);
    }
    __shared__ float red[8];
    int wid = tid >> 6, lane = tid & 63;
    if (lane == 0) { red[wid] = s; red[wid + 4] = sq; }
    __syncthreads();
    float ts = red[0] + red[1] + red[2] + red[3];
    float tq = red[4] + red[5] + red[6] + red[7];
    float mean = ts * (1.0f / 1024.0f);
    float var = tq * (1.0f / 1024.0f) - mean * mean;
    float rstd = rsqrtf(var + 1e-5f);
    float4 g = ((const float4*)gam)[tid];
    float4 b = ((const float4*)bet)[tid];
    u16x4 o;
    o[0] = f2bfn((v.x - mean) * rstd * g.x + b.x);
    o[1] = f2bfn((v.y - mean) * rstd * g.y + b.y);
    o[2] = f2bfn((v.z - mean) * rstd * g.z + b.z);
    o[3] = f2bfn((v.w - mean) * rstd * g.w + b.w);
    *(u16x4*)(out + (size_t)row * 1024 + (tid << 2)) = o;
}

// ---------------- gemm256: 256x256 tile, BK=64, 8 waves (2Mx4N), phased schedule (T1+T2+T3+T4+T5)
// EPI 0: out bf16 = acc+bias      EPI 2: out bf16 = gelu(acc+bias)
template <int EPI>
__global__ __launch_bounds__(512, 2) void gemm256(const u16* __restrict__ A, const u16* __restrict__ Bt,
                                                  const float* __restrict__ bias,
                                                  u16* __restrict__ outb, int M, int N, int K) {
    __shared__ __align__(16) u16 lds[65536];   // 128 KB
    const int tid = threadIdx.x;
    const int lane = tid & 63, wid = tid >> 6;
    const int cl = lane & 15, g4 = lane >> 4;
    const int wr = wid >> 2, wc = wid & 3;     // 2 x 4 wave grid
    const int gx = gridDim.x;
    const int lid = blockIdx.y * gx + blockIdx.x;
    const int per8 = (gx * gridDim.y) >> 3;
    const int newlin = (lid & 7) * per8 + (lid >> 3);
    const int m0 = (newlin / gx) << 8;
    const int n0 = (newlin % gx) << 8;
    const int NT = K >> 6;
    f32x4 acc[8][4] = {};
    const int r0 = tid >> 3;          const int gc0 = (tid & 7) ^ (r0 & 7);
    const int r1 = (tid + 512) >> 3;  const int gc1 = (tid & 7) ^ (r1 & 7);
    const int wub = wid << 10;        // wave-uniform LDS byte base

    auto stageHalf = [&](int buf, int mat, int h, int kt) {
        const u16* src = mat ? Bt : A;
        const int base0 = mat ? n0 : m0;
        char* d = (char*)lds + buf * 65536 + mat * 32768 + h * 16384 + wub;
        gl_lds16(src + (size_t)(base0 + h * 128 + r0) * K + (kt << 6) + (gc0 << 3), d);
        gl_lds16(src + (size_t)(base0 + h * 128 + r1) * K + (kt << 6) + (gc1 << 3), d + 8192);
    };

    stageHalf(0, 0, 0, 0); stageHalf(0, 0, 1, 0);
    stageHalf(0, 1, 0, 0); stageHalf(0, 1, 1, 0);
    asm volatile("s_waitcnt vmcnt(0)" ::: "memory");
    __builtin_amdgcn_s_barrier();

    for (int t = 0; t < NT; ++t) {
        const int buf = t & 1, nbuf = buf ^ 1;
        const bool more = (t + 1 < NT);
        const int abase = buf * 65536 + wr * 16384;
        const int bbase = buf * 65536 + 32768 + (wc >> 1) * 16384;
        bf16x8 bfr[4][2];
        #pragma unroll
        for (int q = 0; q < 4; ++q) {
            bf16x8 afr[2][2];
            #pragma unroll
            for (int di = 0; di < 2; ++di)
                #pragma unroll
                for (int ks = 0; ks < 2; ++ks) {
                    int row = q * 32 + di * 16 + cl;
                    int gr = ks * 4 + g4;
                    afr[di][ks] = *(const bf16x8*)((char*)lds + abase + (((row << 3) + (gr ^ (row & 7))) << 4));
                }
            if (q == 0) {
                #pragma unroll
                for (int j = 0; j < 4; ++j)
                    #pragma unroll
                    for (int ks = 0; ks < 2; ++ks) {
                        int row = ((wc & 1) << 6) + j * 16 + cl;
                        int gr = ks * 4 + g4;
                        bfr[j][ks] = *(const bf16x8*)((char*)lds + bbase + (((row << 3) + (gr ^ (row & 7))) << 4));
                    }
            }
            if (more) stageHalf(nbuf, q >> 1, q & 1, t + 1);   // A-h0, A-h1, B-h0, B-h1
            __builtin_amdgcn_s_barrier();
            asm volatile("s_waitcnt lgkmcnt(0)" ::: "memory");
            __builtin_amdgcn_sched_barrier(0);
            __builtin_amdgcn_s_setprio(1);
            #pragma unroll
            for (int di = 0; di < 2; ++di)
                #pragma unroll
                for (int j = 0; j < 4; ++j)
                    #pragma unroll
                    for (int ks = 0; ks < 2; ++ks)
                        acc[q * 2 + di][j] = __builtin_amdgcn_mfma_f32_16x16x32_bf16(
                            afr[di][ks], bfr[j][ks], acc[q * 2 + di][j], 0, 0, 0);
            __builtin_amdgcn_s_setprio(0);
            if (q == 3 && more) asm volatile("s_waitcnt vmcnt(0)" ::: "memory");
            __builtin_amdgcn_s_barrier();
            if (q == 3) __builtin_amdgcn_sched_barrier(0);
        }
    }
    #pragma unroll
    for (int i = 0; i < 8; ++i)
        #pragma unroll
        for (int j = 0; j < 4; ++j) {
            int row = m0 + wr * 128 + i * 16 + g4 * 4;
            int col = n0 + wc * 64 + j * 16 + cl;
            float bc = bias[col];
            #pragma unroll
            for (int rr = 0; rr < 4; ++rr) {
                float v = acc[i][j][rr] + bc;
                size_t idx = (size_t)(row + rr) * N + col;
                if constexpr (EPI == 0) {
                    outb[idx] = f2bfn(v);
                } else {
                    float tg = 0.7978845608f * (v + 0.044715f * v * v * v);
                    outb[idx] = f2bfn(v / (1.0f + exp2f(tg * -2.88539008f)));  // v*sigmoid(2t)
                }
            }
        }
}

// ---------------- gemm256r: gemm256 with split-K via grid.z (FFN2).
// z == 0: out f32 = acc + bias + res.   z > 0: bf16 raw partial at poutb + (z-1)*M*N.
__global__ __launch_bounds__(512, 2) void gemm256r(const u16* __restrict__ A, const u16* __restrict__ Bt,
                                                   const float* __restrict__ bias,
                                                   const float* __restrict__ res,
                                                   float* __restrict__ outf, u16* __restrict__ poutb,
                                                   int M, int N, int K) {
    __shared__ __align__(16) u16 lds[65536];   // 128 KB
    const int tid = threadIdx.x;
    const int lane = tid & 63, wid = tid >> 6;
    const int cl = lane & 15, g4 = lane >> 4;
    const int wr = wid >> 2, wc = wid & 3;     // 2 x 4 wave grid
    const int gx = gridDim.x;
    const int lid = blockIdx.y * gx + blockIdx.x;
    const int per8 = (gx * gridDim.y) >> 3;
    const int newlin = (lid & 7) * per8 + (lid >> 3);
    const int m0 = (newlin / gx) << 8;
    const int n0 = (newlin % gx) << 8;
    const int kchunk = K / gridDim.z;
    const int kbase = blockIdx.z * kchunk;
    const int NT = kchunk >> 6;
    f32x4 acc[8][4] = {};
    const int r0 = tid >> 3;          const int gc0 = (tid & 7) ^ (r0 & 7);
    const int r1 = (tid + 512) >> 3;  const int gc1 = (tid & 7) ^ (r1 & 7);
    const int wub = wid << 10;

    auto stageHalf = [&](int buf, int mat, int h, int kt) {
        const u16* src = mat ? Bt : A;
        const int base0 = mat ? n0 : m0;
        char* d = (char*)lds + buf * 65536 + mat * 32768 + h * 16384 + wub;
        gl_lds16(src + (size_t)(base0 + h * 128 + r0) * K + kbase + (kt << 6) + (gc0 << 3), d);
        gl_lds16(src + (size_t)(base0 + h * 128 + r1) * K + kbase + (kt << 6) + (gc1 << 3), d + 8192);
    };

    stageHalf(0, 0, 0, 0); stageHalf(0, 0, 1, 0);
    stageHalf(0, 1, 0, 0); stageHalf(0, 1, 1, 0);
    asm volatile("s_waitcnt vmcnt(0)" ::: "memory");
    __builtin_amdgcn_s_barrier();

    for (int t = 0; t < NT; ++t) {
        const int buf = t & 1, nbuf = buf ^ 1;
        const bool more = (t + 1 < NT);
        const int abase = buf * 65536 + wr * 16384;
        const int bbase = buf * 65536 + 32768 + (wc >> 1) * 16384;
        bf16x8 bfr[4][2];
        #pragma unroll
        for (int q = 0; q < 4; ++q) {
            bf16x8 afr[2][2];
            #pragma unroll
            for (int di = 0; di < 2; ++di)
                #pragma unroll
                for (int ks = 0; ks < 2; ++ks) {
                    int row = q * 32 + di * 16 + cl;
                    int gr = ks * 4 + g4;
                    afr[di][ks] = *(const bf16x8*)((char*)lds + abase + (((row << 3) + (gr ^ (row & 7))) << 4));
                }
            if (q == 0) {
                #pragma unroll
                for (int j = 0; j < 4; ++j)
                    #pragma unroll
                    for (int ks = 0; ks < 2; ++ks) {
                        int row = ((wc & 1) << 6) + j * 16 + cl;
                        int gr = ks * 4 + g4;
                        bfr[j][ks] = *(const bf16x8*)((char*)lds + bbase + (((row << 3) + (gr ^ (row & 7))) << 4));
                    }
            }
            if (more) stageHalf(nbuf, q >> 1, q & 1, t + 1);
            __builtin_amdgcn_s_barrier();
            asm volatile("s_waitcnt lgkmcnt(0)" ::: "memory");
            __builtin_amdgcn_sched_barrier(0);
            __builtin_amdgcn_s_setprio(1);
            #pragma unroll
            for (int di = 0; di < 2; ++di)
                #pragma unroll
                for (int j = 0; j < 4; ++j)
                    #pragma unroll
                    for (int ks = 0; ks < 2; ++ks)
                        acc[q * 2 + di][j] = __builtin_amdgcn_mfma_f32_16x16x32_bf16(
                            afr[di][ks], bfr[j][ks], acc[q * 2 + di][j], 0, 0, 0);
            __builtin_amdgcn_s_setprio(0);
            if (q == 3 && more) asm volatile("s_waitcnt vmcnt(0)" ::: "memory");
            __builtin_amdgcn_s_barrier();
            if (q == 3) __builtin_amdgcn_sched_barrier(0);
        }
    }
    if (blockIdx.z == 0) {
        #pragma unroll
        for (int i = 0; i < 8; ++i)
            #pragma unroll
            for (int j = 0; j < 4; ++j) {
                int row = m0 + wr * 128 + i * 16 + g4 * 4;
                int col = n0 + wc * 64 + j * 16 + cl;
                float bc = bias[col];
                #pragma unroll
                for (int rr = 0; rr < 4; ++rr) {
                    size_t idx = (size_t)(row + rr) * N + col;
                    outf[idx] = acc[i][j][rr] + bc + res[idx];
                }
            }
    } else {
        const size_t pbase = (size_t)(blockIdx.z - 1) * ((size_t)M * N);
        #pragma unroll
        for (int i = 0; i < 8; ++i)
            #pragma unroll
            for (int j = 0; j < 4; ++j) {
                int row = m0 + wr * 128 + i * 16 + g4 * 4;
                int col = n0 + wc * 64 + j * 16 + cl;
                #pragma unroll
                for (int rr = 0; rr < 4; ++rr)
                    poutb[pbase + (size_t)(row + rr) * N + col] = f2bfn(acc[i][j][rr]);
            }
    }
}

// ---------------- GEMM 128^2 (m97 + T1 + T4 + granule permute): used for wo
template <int EPI>
__global__ __launch_bounds__(256) void gemm_bt(const u16* __restrict__ A, const u16* __restrict__ Bt,
                                               const float* __restrict__ bias,
                                               const float* __restrict__ res,
                                               u16* __restrict__ outb, float* __restrict__ outf,
                                               u16* __restrict__ poutb,
                                               int M, int N, int K) {
    __shared__ __align__(16) u16 As[3][4096];
    __shared__ __align__(16) u16 Bs[3][4096];
    const int tid = threadIdx.x;
    const int lane = tid & 63, wid = tid >> 6;
    const int g = lane >> 4, cl = lane & 15;
    const int wr = wid >> 1, wc = wid & 1;
    const int gx = gridDim.x;
    const int lid = blockIdx.y * gx + blockIdx.x;
    const int per8 = (gx * gridDim.y) >> 3;
    const int newlin = (lid & 7) * per8 + (lid >> 3);
    const int m0 = (newlin / gx) << 7;
    const int n0 = (newlin % gx) << 7;
    const int kchunk = K / gridDim.z;
    const int kbase = blockIdx.z * kchunk;
    const int NT = kchunk >> 5;
    f32x4 acc[4][4] = {};
    const int grow = tid >> 2;
    const int gcol = (tid & 3) ^ ((tid >> 3) & 3);

    auto stage = [&](int buf, int kt) {
        const int ko = kbase + (kt << 5);
        gl_lds16(A + (size_t)(m0 + grow) * K + ko + (gcol << 3),       &As[buf][wid << 9]);
        gl_lds16(A + (size_t)(m0 + grow + 64) * K + ko + (gcol << 3),  &As[buf][(wid << 9) + 2048]);
        gl_lds16(Bt + (size_t)(n0 + grow) * K + ko + (gcol << 3),      &Bs[buf][wid << 9]);
        gl_lds16(Bt + (size_t)(n0 + grow + 64) * K + ko + (gcol << 3), &Bs[buf][(wid << 9) + 2048]);
    };

    stage(0, 0);
    stage(1, 1);
    for (int kt = 0; kt < NT; ++kt) {
        if (kt + 1 < NT) asm volatile("s_waitcnt vmcnt(4)" ::: "memory");
        else             asm volatile("s_waitcnt vmcnt(0)" ::: "memory");
        __builtin_amdgcn_s_barrier();
        __builtin_amdgcn_sched_barrier(0);
        if (kt + 2 < NT) stage((kt + 2) % 3, kt + 2);
        const int cb = kt % 3;
        bf16x8 a[4], b[4];
        #pragma unroll
        for (int i = 0; i < 4; ++i) {
            int row = (wr << 6) + (i << 4) + cl;
            a[i] = *(const bf16x8*)&As[cb][((row << 2) + (g ^ ((row >> 1) & 3))) << 3];
        }
        #pragma unroll
        for (int j = 0; j < 4; ++j) {
            int row = (wc << 6) + (j << 4) + cl;
            b[j] = *(const bf16x8*)&Bs[cb][((row << 2) + (g ^ ((row >> 1) & 3))) << 3];
        }
        __builtin_amdgcn_s_setprio(1);
        #pragma unroll
        for (int i = 0; i < 4; ++i)
            #pragma unroll
            for (int j = 0; j < 4; ++j)
                acc[i][j] = __builtin_amdgcn_mfma_f32_16x16x32_bf16(a[i], b[j], acc[i][j], 0, 0, 0);
        __builtin_amdgcn_s_setprio(0);
    }
    if (blockIdx.z == 0) {
        #pragma unroll
        for (int i = 0; i < 4; ++i)
            #pragma unroll
            for (int j = 0; j < 4; ++j) {
                int row = m0 + (wr << 6) + (i << 4) + (g << 2);
                int col = n0 + (wc << 6) + (j << 4) + cl;
                float bc = bias[col];
                #pragma unroll
                for (int rr = 0; rr < 4; ++rr) {
                    float v = acc[i][j][rr] + bc;
                    size_t idx = (size_t)(row + rr) * N + col;
                    outf[idx] = v + res[idx];
                }
            }
    } else {
        const size_t pbase = (size_t)(blockIdx.z - 1) * ((size_t)M * N);
        #pragma unroll
        for (int i = 0; i < 4; ++i)
            #pragma unroll
            for (int j = 0; j < 4; ++j) {
                int row = m0 + (wr << 6) + (i << 4) + (g << 2);
                int col = n0 + (wc << 6) + (j << 4) + cl;
                #pragma unroll
                for (int rr = 0; rr < 4; ++rr)
                    poutb[pbase + (size_t)(row + rr) * N + col] = f2bfn(acc[i][j][rr]);
            }
    }
}

// ---------------- split-K reduce: out += sum of bf16 partials (each 4096*1024 elements)
__global__ __launch_bounds__(256) void reduce_addb(float* __restrict__ out, const u16* __restrict__ p,
                                                   int nparts) {
    int i = blockIdx.x * 256 + threadIdx.x;   // x4 elements
    float4 a = ((const float4*)out)[i];
    for (int j = 0; j < nparts; ++j) {
        u16x4 v = *(const u16x4*)(p + (size_t)j * 4194304 + ((size_t)i << 2));
        a.x += bf2f(v[0]); a.y += bf2f(v[1]); a.z += bf2f(v[2]); a.w += bf2f(v[3]);
    }
    ((float4*)out)[i] = a;
}

// ---------------- RoPE for q,k: qkv[4096][3072] -> qr/kr [BH][S][64]
// q pre-scaled by 0.125 * log2(e) so attention uses exp2 directly
__global__ __launch_bounds__(256) void rope_qk(const u16* __restrict__ qkv,
                                               const float* __restrict__ cost,
                                               const float* __restrict__ sint,
                                               u16* __restrict__ qr, u16* __restrict__ kr) {
    int tid = threadIdx.x;
    int rowid = (blockIdx.x << 4) + (tid >> 4);  // bh*2048+s over [0,65536)
    int j = tid & 15;
    int half = j >> 3, jj = j & 7;
    int b = rowid >> 15;
    int h = (rowid >> 11) & 15;
    int s = rowid & 2047;
    size_t qbase = (size_t)((b << 11) + s) * 3072 + (h << 6);
    float cf[4], sf_[4];
    {
        float4 c = *(const float4*)(cost + (s << 5) + (jj << 2));
        float4 sn = *(const float4*)(sint + (s << 5) + (jj << 2));
        cf[0] = c.x; cf[1] = c.y; cf[2] = c.z; cf[3] = c.w;
        sf_[0] = sn.x; sf_[1] = sn.y; sf_[2] = sn.z; sf_[3] = sn.w;
    }
    size_t obase = (size_t)rowid * 64 + (half << 5) + (jj << 2);
    {
        u16x8 v = *(const u16x8*)(qkv + qbase + (jj << 3));
        u16x4 o;
        #pragma unroll
        for (int m2 = 0; m2 < 4; ++m2) {
            float e = bf2f(v[2 * m2]), od = bf2f(v[2 * m2 + 1]);
            float val = (half == 0) ? (e * cf[m2] - od * sf_[m2]) : (e * sf_[m2] + od * cf[m2]);
            o[m2] = f2bfn(val * 0.1803368801f);  // 0.125 * log2(e)
        }
        *(u16x4*)(qr + obase) = o;
    }
    {
        u16x8 v = *(const u16x8*)(qkv + qbase + 1024 + (jj << 3));
        u16x4 o;
        #pragma unroll
        for (int m2 = 0; m2 < 4; ++m2) {
            float e = bf2f(v[2 * m2]), od = bf2f(v[2 * m2 + 1]);
            float val = (half == 0) ? (e * cf[m2] - od * sf_[m2]) : (e * sf_[m2] + od * cf[m2]);
            o[m2] = f2bfn(val);
        }
        *(u16x4*)(kr + obase) = o;
    }
}

// ---------------- V transpose: qkv v-part -> vt[BH][64 d][2048 s]
__global__ __launch_bounds__(256) void v_transpose(const u16* __restrict__ qkv,
                                                   u16* __restrict__ vt) {
    __shared__ __align__(16) u16 tl[64 * 80];
    int stile = blockIdx.x, bh = blockIdx.y;
    int b = bh >> 4, h = bh & 15;
    int tid = threadIdx.x;
    #pragma unroll
    for (int i = 0; i < 2; ++i) {
        int slot = tid + (i << 8);
        int srow = slot >> 3, c = slot & 7;
        u16x8 v = *(const u16x8*)(qkv + (size_t)((b << 11) + (stile << 6) + srow) * 3072 + 2048 + (h << 6) + (c << 3));
        *(u16x8*)(tl + srow * 80 + (c << 3)) = v;
    }
    __syncthreads();
    #pragma unroll
    for (int i = 0; i < 2; ++i) {
        int slot = tid + (i << 8);
        int drow = slot >> 3, c = slot & 7;
        u16x8 o;
        #pragma unroll
        for (int m2 = 0; m2 < 8; ++m2) o[m2] = tl[(c * 8 + m2) * 80 + drow];
        *(u16x8*)(vt + ((size_t)bh * 64 + drow) * 2048 + (stile << 6) + (c << 3)) = o;
    }
}

// ---------------- flash attention (best-measured R12 config): triangle-paired blocks with XCD
// head affinity, reg-staged double-buffered K/V (T14 issue-early/write-late, 1 barrier/tile),
// swapped QK^T, float mask, cvt_pk P-pack.
__global__ __launch_bounds__(256) void attn_kernel(const u16* __restrict__ Q, const u16* __restrict__ Kd,
                                                   const u16* __restrict__ Vt, const float* __restrict__ maskf,
                                                   u16* __restrict__ ctx) {
    __shared__ __align__(16) u16 Ks[2][4096];
    __shared__ __align__(16) u16 Vs[2][4096];
    __shared__ __align__(16) u16 Ps[4096];
    const int tid = threadIdx.x, lane = tid & 63, w = tid >> 6;
    const int g = lane >> 4, cl = lane & 15;
    const int lid = blockIdx.y * 16 + blockIdx.x;   // grid (16,32) = 512 blocks
    const int xcd = lid & 7, slot = lid >> 3;       // slot in [0,64)
    const int bh = xcd * 4 + (slot >> 4);           // 4 heads per XCD (K/V L2-resident)
    const int pair = slot & 15;                     // 16 pair-blocks per head
    const int b = bh >> 4, h = bh & 15;
    const u16* Kb = Kd + (size_t)bh * 2048 * 64;
    const u16* Vb = Vt + (size_t)bh * 64 * 2048;
    const int srow0 = tid >> 3, sc0 = tid & 7;
    const int srow1 = (tid + 256) >> 3, sc1 = sc0;
    bf16x8 onesb;
    #pragma unroll
    for (int i2 = 0; i2 < 8; ++i2) onesb[i2] = (__bf16)1.0f;
    // P write base: row = q = cl, 8B slot for (ct,g) at granule (ct*2+(g>>1)) ^ (cl&7)
    char* const pwb = (char*)Ps + w * 2048 + cl * 128 + ((g & 1) << 3);

    #pragma unroll
    for (int ci = 0; ci < 2; ++ci) {
        const int qb = (ci == 0) ? (31 - pair) : pair;  // heavy chunk first
        const size_t qoff = ((size_t)bh * 2048 + qb * 64 + w * 16 + cl) * 64;
        const bf16x8 qa0 = *(const bf16x8*)(Q + qoff + (g << 3));
        const bf16x8 qa1 = *(const bf16x8*)(Q + qoff + 32 + (g << 3));
        const int qrow = qb * 64 + w * 16 + cl;     // this lane's q row (S^T layout)
        f32x4 acc[4] = {};
        f32x4 lsum = {};

        u16x8 k0a = *(const u16x8*)(Kb + (size_t)srow0 * 64 + (sc0 << 3));
        u16x8 k0b = *(const u16x8*)(Kb + (size_t)srow1 * 64 + (sc1 << 3));
        u16x8 v0a = *(const u16x8*)(Vb + (size_t)srow0 * 2048 + (sc0 << 3));
        u16x8 v0b = *(const u16x8*)(Vb + (size_t)srow1 * 2048 + (sc1 << 3));
        __syncthreads();  // previous chunk's LDS readers done
        *(u16x8*)((char*)&Ks[0][0] + srow0 * 128 + ((sc0 ^ (srow0 & 7)) << 4)) = k0a;
        *(u16x8*)((char*)&Ks[0][0] + srow1 * 128 + ((sc1 ^ (srow1 & 7)) << 4)) = k0b;
        *(u16x8*)((char*)&Vs[0][0] + srow0 * 128 + ((sc0 ^ (srow0 & 7)) << 4)) = v0a;
        *(u16x8*)((char*)&Vs[0][0] + srow1 * 128 + ((sc1 ^ (srow1 & 7)) << 4)) = v0b;
        __syncthreads();

        int cur = 0;
        for (int t = 0; t <= qb; ++t) {
            const bool more = (t < qb);
            u16x8 rka, rkb, rva, rvb;
            if (more) {
                const u16* Kg = Kb + (size_t)(t + 1) * 64 * 64;
                rka = *(const u16x8*)(Kg + (size_t)srow0 * 64 + (sc0 << 3));
                rkb = *(const u16x8*)(Kg + (size_t)srow1 * 64 + (sc1 << 3));
                rva = *(const u16x8*)(Vb + (size_t)srow0 * 2048 + (t + 1) * 64 + (sc0 << 3));
                rvb = *(const u16x8*)(Vb + (size_t)srow1 * 2048 + (t + 1) * 64 + (sc1 << 3));
            }
            // swapped QK^T: sf[ct][rr] = S[q = qrow][k = t*64 + ct*16 + g*4 + rr]
            f32x4 sf[4];
            __builtin_amdgcn_s_setprio(1);
            #pragma unroll
            for (int ct = 0; ct < 4; ++ct) {
                f32x4 s = {};
                int krow = ct * 16 + cl;
                bf16x8 kb0 = *(const bf16x8*)((char*)&Ks[cur][0] + krow * 128 + ((g ^ (krow & 7)) << 4));
                bf16x8 kb1 = *(const bf16x8*)((char*)&Ks[cur][0] + krow * 128 + (((4 + g) ^ (krow & 7)) << 4));
                s = __builtin_amdgcn_mfma_f32_16x16x32_bf16(kb0, qa0, s, 0, 0, 0);
                s = __builtin_amdgcn_mfma_f32_16x16x32_bf16(kb1, qa1, s, 0, 0, 0);
                sf[ct] = s;
            }
            __builtin_amdgcn_s_setprio(0);
            // p = exp2(s) * mask * causal; pack 4 consecutive k as 2 cvt_pk -> one 8B write
            const bool diag = (t == qb);
            #pragma unroll
            for (int ct = 0; ct < 4; ++ct) {
                const int kc0 = t * 64 + ct * 16 + (g << 2);
                const float4 mv = *(const float4*)(maskf + (b << 11) + kc0);
                float p0 = exp2f(sf[ct][0]) * mv.x;
                float p1 = exp2f(sf[ct][1]) * mv.y;
                float p2 = exp2f(sf[ct][2]) * mv.z;
                float p3 = exp2f(sf[ct][3]) * mv.w;
                if (diag) {
                    p0 = (kc0 + 0 <= qrow) ? p0 : 0.0f;
                    p1 = (kc0 + 1 <= qrow) ? p1 : 0.0f;
                    p2 = (kc0 + 2 <= qrow) ? p2 : 0.0f;
                    p3 = (kc0 + 3 <= qrow) ? p3 : 0.0f;
                }
                u32 lo, hi;
                asm("v_cvt_pk_bf16_f32 %0, %1, %2" : "=v"(lo) : "v"(p0), "v"(p1));
                asm("v_cvt_pk_bf16_f32 %0, %1, %2" : "=v"(hi) : "v"(p2), "v"(p3));
                uint2 pk; pk.x = lo; pk.y = hi;
                *(uint2*)(pwb + ((((ct << 1) + (g >> 1)) ^ (cl & 7)) << 4)) = pk;
            }
            // PV + row-sum (ones-MFMA) from buf[cur]
            __builtin_amdgcn_s_setprio(1);
            #pragma unroll
            for (int kc = 0; kc < 2; ++kc) {
                bf16x8 pa = *(const bf16x8*)((char*)Ps + w * 2048 + cl * 128 + (((kc * 4 + g) ^ (cl & 7)) << 4));
                lsum = __builtin_amdgcn_mfma_f32_16x16x32_bf16(pa, onesb, lsum, 0, 0, 0);
                #pragma unroll
                for (int n = 0; n < 4; ++n) {
                    int vrow = n * 16 + cl;
                    bf16x8 vb = *(const bf16x8*)((char*)&Vs[cur][0] + vrow * 128 + (((kc * 4 + g) ^ (vrow & 7)) << 4));
                    acc[n] = __builtin_amdgcn_mfma_f32_16x16x32_bf16(pa, vb, acc[n], 0, 0, 0);
                }
            }
            __builtin_amdgcn_s_setprio(0);
            if (more) {
                *(u16x8*)((char*)&Ks[cur ^ 1][0] + srow0 * 128 + ((sc0 ^ (srow0 & 7)) << 4)) = rka;
                *(u16x8*)((char*)&Ks[cur ^ 1][0] + srow1 * 128 + ((sc1 ^ (srow1 & 7)) << 4)) = rkb;
                *(u16x8*)((char*)&Vs[cur ^ 1][0] + srow0 * 128 + ((sc0 ^ (srow0 & 7)) << 4)) = rva;
                *(u16x8*)((char*)&Vs[cur ^ 1][0] + srow1 * 128 + ((sc1 ^ (srow1 & 7)) << 4)) = rvb;
                __syncthreads();
            }
            cur ^= 1;
        }
        #pragma unroll
        for (int n = 0; n < 4; ++n)
            #pragma unroll
            for (int rr = 0; rr < 4; ++rr) {
                int token = (b << 11) + qb * 64 + w * 16 + g * 4 + rr;
                int col = (h << 6) + n * 16 + cl;
                ctx[(size_t)token * 1024 + col] = f2bfn(acc[n][rr] / lsum[rr]);
            }
    }
}

extern "C" void kernel_launch(void* const* d_in, const int* in_sizes, int n_in,
                              void* d_out, int out_size, void* d_ws, size_t ws_size,
                              hipStream_t stream) {
    const float* x   = (const float*)d_in[0];
    const int* mask  = (const int*)d_in[1];
    const float* wq  = (const float*)d_in[2];
    const float* bq  = (const float*)d_in[3];
    const float* wk  = (const float*)d_in[4];
    const float* bk  = (const float*)d_in[5];
    const float* wv  = (const float*)d_in[6];
    const float* bv  = (const float*)d_in[7];
    const float* wo  = (const float*)d_in[8];
    const float* bo  = (const float*)d_in[9];
    const float* w1  = (const float*)d_in[10];
    const float* b1  = (const float*)d_in[11];
    const float* w2  = (const float*)d_in[12];
    const float* b2  = (const float*)d_in[13];
    const float* g1  = (const float*)d_in[14];
    const float* be1 = (const float*)d_in[15];
    const float* g2  = (const float*)d_in[16];
    const float* be2 = (const float*)d_in[17];
    float* out = (float*)d_out;
    char* ws = (char*)d_ws;

    // ws map (109.59 MB total, overlays noted):
    u16* wqkvT  = (u16*)(ws + 0);            //  6 MB, whole call
    u16* woT    = (u16*)(ws + 6291456);      //  2 MB
    u16* w1T    = (u16*)(ws + 8388608);      //  8 MB
    u16* w2T    = (u16*)(ws + 16777216);     //  8 MB
    float* bqkv = (float*)(ws + 25165824);   // 12 KB
    float* cost = (float*)(ws + 25178112);   // 256 KB
    float* sint = (float*)(ws + 25440256);   // 256 KB
    u16* xn     = (u16*)(ws + 25702400);     //  8 MB (LN1 out; reused for LN2 out)
    float* x2   = (float*)(ws + 34091008);   // 16 MB (residual-2 base; first written by wo-gemm)
    float* maskf= (float*)(ws + 34091008);   // 16 KB overlay on x2 head (dead once wo-gemm writes x2)
    u16* qkv    = (u16*)(ws + 50868224);     // 24 MB (dead after v_transpose)
    u16* ffh    = (u16*)(ws + 50868224);     // 32 MB overlay on qkv+qr; spans to 84422656
    u16* qr     = (u16*)(ws + 76034048);     //  8 MB (dead after attn)
    u16* kr     = (u16*)(ws + 84422656);     //  8 MB (dead after attn)
    u16* vt     = (u16*)(ws + 92811264);     //  8 MB (dead after attn)
    u16* ctx    = (u16*)(ws + 101199872);    //  8 MB (dead after wo-gemm)
    // bf16 split-K partials: 3 x 8 MB on kr+vt+ctx. DISJOINT from ffh (ends 84422656).
    u16* partb  = (u16*)(ws + 84422656);

    transpose_cvt4<<<dim3(32, 32, 4), 256, 0, stream>>>(wq, wk, wv, wo,
                                                        wqkvT, wqkvT + 1024 * 1024, wqkvT + 2048 * 1024, woT);
    transpose_cvt2<<<dim3(128, 32, 2), 256, 0, stream>>>(w1, w2, w1T, w2T);
    prep_kernel<<<256, 256, 0, stream>>>(bq, bk, bv, bqkv, mask, maskf, cost, sint);

    ln_kernel<<<4096, 256, 0, stream>>>(x, g1, be1, xn);
    gemm256<0><<<dim3(12, 16), 512, 0, stream>>>(xn, wqkvT, bqkv, qkv, 4096, 3072, 1024);
    rope_qk<<<4096, 256, 0, stream>>>(qkv, cost, sint, qr, kr);
    v_transpose<<<dim3(32, 32), 256, 0, stream>>>(qkv, vt);
    attn_kernel<<<dim3(16, 32), 256, 0, stream>>>(qr, kr, vt, maskf, ctx);
    gemm_bt<1><<<dim3(8, 32, 2), 256, 0, stream>>>(ctx, woT, bo, x, nullptr, x2, partb, 4096, 1024, 1024);
    ln_fuse<<<4096, 256, 0, stream>>>(x2, partb, g2, be2, xn);
    gemm256<2><<<dim3(16, 16), 512, 0, stream>>>(xn, w1T, b1, ffh, 4096, 4096, 1024);
    gemm256r<<<dim3(4, 16, 4), 512, 0, stream>>>(ffh, w2T, b2, x2, out, partb, 4096, 1024, 4096);
    reduce_addb<<<4096, 256, 0, stream>>>(out, partb, 3);
}

// Round 17
// 240.175 us; speedup vs baseline: 1.3448x; 1.0041x over previous
//
#include <hip/hip_runtime.h>

typedef unsigned short u16;
typedef unsigned int u32;
typedef __attribute__((ext_vector_type(8))) u16 u16x8;
typedef __attribute__((ext_vector_type(4))) u16 u16x4;
typedef __attribute__((ext_vector_type(8))) __bf16 bf16x8;
typedef __attribute__((ext_vector_type(4))) float f32x4;

static __device__ __forceinline__ float bf2f(u16 u) {
    union { u32 i; float f; } v; v.i = ((u32)u) << 16; return v.f;
}
static __device__ __forceinline__ u16 f2bf(float f) {   // manual RNE (cold paths)
    union { float f; u32 i; } v; v.f = f;
    u32 r = v.i + 0x7fffu + ((v.i >> 16) & 1u);
    return (u16)(r >> 16);
}
static __device__ __forceinline__ u16 f2bfn(float f) {  // native cvt (hot paths)
    __bf16 h = (__bf16)f;
    return *(u16*)&h;
}
// async global -> LDS, 16B per lane; ldst must be wave-uniform (HW adds lane*16)
static __device__ __forceinline__ void gl_lds16(const void* gsrc, void* ldst) {
    __builtin_amdgcn_global_load_lds((const __attribute__((address_space(1))) void*)gsrc,
                                     (__attribute__((address_space(3))) void*)ldst, 16, 0, 0);
}

// ---------------- weight transpose + fp32->bf16 convert: out[n][k] = in[k][n]
// batched 1024x1024 variant: z selects (wq,wk,wv,wo)
__global__ __launch_bounds__(256) void transpose_cvt4(const float* __restrict__ w0, const float* __restrict__ w1,
                                                      const float* __restrict__ w2, const float* __restrict__ w3,
                                                      u16* __restrict__ o0, u16* __restrict__ o1,
                                                      u16* __restrict__ o2, u16* __restrict__ o3) {
    __shared__ float t[32][33];
    const float* in; u16* out;
    switch (blockIdx.z) {
        case 0:  in = w0; out = o0; break;
        case 1:  in = w1; out = o1; break;
        case 2:  in = w2; out = o2; break;
        default: in = w3; out = o3; break;
    }
    int k0 = blockIdx.y << 5, n0 = blockIdx.x << 5;
    int r = threadIdx.x >> 3, c4 = threadIdx.x & 7;
    float4 v = *(const float4*)(in + (size_t)(k0 + r) * 1024 + n0 + (c4 << 2));
    t[r][c4 * 4 + 0] = v.x; t[r][c4 * 4 + 1] = v.y;
    t[r][c4 * 4 + 2] = v.z; t[r][c4 * 4 + 3] = v.w;
    __syncthreads();
    u16x4 o;
    o[0] = f2bf(t[c4 * 4 + 0][r]); o[1] = f2bf(t[c4 * 4 + 1][r]);
    o[2] = f2bf(t[c4 * 4 + 2][r]); o[3] = f2bf(t[c4 * 4 + 3][r]);
    *(u16x4*)(out + (size_t)(n0 + r) * 1024 + k0 + (c4 << 2)) = o;
}

// w1 (1024x4096) and w2 (4096x1024) in one launch: grid (128, 32, 2)
__global__ __launch_bounds__(256) void transpose_cvt2(const float* __restrict__ w1, const float* __restrict__ w2,
                                                      u16* __restrict__ o1, u16* __restrict__ o2) {
    __shared__ float t[32][33];
    const int zz = blockIdx.z;
    const float* in = zz ? w2 : w1;
    u16* out = zz ? o2 : o1;
    const int K = zz ? 4096 : 1024, N = zz ? 1024 : 4096;
    int k0, n0;
    if (zz) { k0 = blockIdx.x << 5; n0 = blockIdx.y << 5; }
    else    { n0 = blockIdx.x << 5; k0 = blockIdx.y << 5; }
    int r = threadIdx.x >> 3, c4 = threadIdx.x & 7;
    float4 v = *(const float4*)(in + (size_t)(k0 + r) * N + n0 + (c4 << 2));
    t[r][c4 * 4 + 0] = v.x; t[r][c4 * 4 + 1] = v.y;
    t[r][c4 * 4 + 2] = v.z; t[r][c4 * 4 + 3] = v.w;
    __syncthreads();
    u16x4 o;
    o[0] = f2bf(t[c4 * 4 + 0][r]); o[1] = f2bf(t[c4 * 4 + 1][r]);
    o[2] = f2bf(t[c4 * 4 + 2][r]); o[3] = f2bf(t[c4 * 4 + 3][r]);
    *(u16x4*)(out + (size_t)(n0 + r) * K + k0 + (c4 << 2)) = o;
}

// ---------------- prep: rope table + qkv bias concat + float mask (one launch, grid 256x256)
__global__ void prep_kernel(const float* __restrict__ bq, const float* __restrict__ bk,
                            const float* __restrict__ bv, float* __restrict__ bqkv,
                            const int* __restrict__ mask, float* __restrict__ maskf,
                            float* __restrict__ cost, float* __restrict__ sint) {
    int idx = blockIdx.x * 256 + threadIdx.x;  // 65536 = 2048 * 32
    int s = idx >> 5, f = idx & 31;
    float inv = powf(10000.0f, -((float)(2 * f)) / 64.0f);
    float a = (float)s * inv;
    cost[idx] = cosf(a);
    sint[idx] = sinf(a);
    if (idx < 3072) {
        float v = (idx < 1024) ? bq[idx] : (idx < 2048 ? bk[idx - 1024] : bv[idx - 2048]);
        bqkv[idx] = v;
    }
    if (idx < 4096) maskf[idx] = (float)mask[idx];
}

// ---------------- LayerNorm: 1 block / row of 1024, output bf16
__global__ __launch_bounds__(256) void ln_kernel(const float* __restrict__ x,
                                                 const float* __restrict__ gam,
                                                 const float* __restrict__ bet,
                                                 u16* __restrict__ out) {
    int row = blockIdx.x, tid = threadIdx.x;
    float4 v = *((const float4*)(x + (size_t)row * 1024) + tid);
    float s = v.x + v.y + v.z + v.w;
    float sq = v.x * v.x + v.y * v.y + v.z * v.z + v.w * v.w;
    #pragma unroll
    for (int off = 32; off >= 1; off >>= 1) {
        s += __shfl_xor(s, off);
        sq += __shfl_xor(sq, off);
    }
    __shared__ float red[8];
    int wid = tid >> 6, lane = tid & 63;
    if (lane == 0) { red[wid] = s; red[wid + 4] = sq; }
    __syncthreads();
    float ts = red[0] + red[1] + red[2] + red[3];
    float tq = red[4] + red[5] + red[6] + red[7];
    float mean = ts * (1.0f / 1024.0f);
    float var = tq * (1.0f / 1024.0f) - mean * mean;
    float rstd = rsqrtf(var + 1e-5f);
    float4 g = ((const float4*)gam)[tid];
    float4 b = ((const float4*)bet)[tid];
    u16x4 o;
    o[0] = f2bfn((v.x - mean) * rstd * g.x + b.x);
    o[1] = f2bfn((v.y - mean) * rstd * g.y + b.y);
    o[2] = f2bfn((v.z - mean) * rstd * g.z + b.z);
    o[3] = f2bfn((v.w - mean) * rstd * g.w + b.w);
    *(u16x4*)(out + (size_t)row * 1024 + (tid << 2)) = o;
}

// ---------------- LN2 fused with wo split-K merge: x2 += bf16 partial; xn = LN(x2)
__global__ __launch_bounds__(256) void ln_fuse(float* __restrict__ x2, const u16* __restrict__ part,
                                               const float* __restrict__ gam, const float* __restrict__ bet,
                                               u16* __restrict__ out) {
    int row = blockIdx.x, tid = threadIdx.x;
    float4 v = *((const float4*)(x2 + (size_t)row * 1024) + tid);
    u16x4 pv = *(const u16x4*)(part + (size_t)row * 1024 + (tid << 2));
    v.x += bf2f(pv[0]); v.y += bf2f(pv[1]); v.z += bf2f(pv[2]); v.w += bf2f(pv[3]);
    *((float4*)(x2 + (size_t)row * 1024) + tid) = v;   // residual base for FFN2
    float s = v.x + v.y + v.z + v.w;
    float sq = v.x * v.x + v.y * v.y + v.z * v.z + v.w * v.w;
    #pragma unroll
    for (int off = 32; off >= 1; off >>= 1) {
        s += __shfl_xor(s, off);
        sq += __shfl_xor(sq, off);
    }
    __shared__ float red[8];
    int wid = tid >> 6, lane = tid & 63;
    if (lane == 0) { red[wid] = s; red[wid + 4] = sq; }
    __syncthreads();
    float ts = red[0] + red[1] + red[2] + red[3];
    float tq = red[4] + red[5] + red[6] + red[7];
    float mean = ts * (1.0f / 1024.0f);
    float var = tq * (1.0f / 1024.0f) - mean * mean;
    float rstd = rsqrtf(var + 1e-5f);
    float4 g = ((const float4*)gam)[tid];
    float4 b = ((const float4*)bet)[tid];
    u16x4 o;
    o[0] = f2bfn((v.x - mean) * rstd * g.x + b.x);
    o[1] = f2bfn((v.y - mean) * rstd * g.y + b.y);
    o[2] = f2bfn((v.z - mean) * rstd * g.z + b.z);
    o[3] = f2bfn((v.w - mean) * rstd * g.w + b.w);
    *(u16x4*)(out + (size_t)row * 1024 + (tid << 2)) = o;
}

// ---------------- gemm256: 256x256 tile, BK=64, 8 waves (2Mx4N), phased schedule.
// R17: all of tile t+1's staging issues at phase 0 -> the q==3 vmcnt(0) drain has ~3 phases of
// latency cover and retires nearly free (approximates counted-vmcnt without buffer changes).
// EPI 0: out bf16 = acc+bias      EPI 2: out bf16 = gelu(acc+bias)
template <int EPI>
__global__ __launch_bounds__(512, 2) void gemm256(const u16* __restrict__ A, const u16* __restrict__ Bt,
                                                  const float* __restrict__ bias,
                                                  u16* __restrict__ outb, int M, int N, int K) {
    __shared__ __align__(16) u16 lds[65536];   // 128 KB
    const int tid = threadIdx.x;
    const int lane = tid & 63, wid = tid >> 6;
    const int cl = lane & 15, g4 = lane >> 4;
    const int wr = wid >> 2, wc = wid & 3;     // 2 x 4 wave grid
    const int gx = gridDim.x;
    const int lid = blockIdx.y * gx + blockIdx.x;
    const int per8 = (gx * gridDim.y) >> 3;
    const int newlin = (lid & 7) * per8 + (lid >> 3);
    const int m0 = (newlin / gx) << 8;
    const int n0 = (newlin % gx) << 8;
    const int NT = K >> 6;
    f32x4 acc[8][4] = {};
    const int r0 = tid >> 3;          const int gc0 = (tid & 7) ^ (r0 & 7);
    const int r1 = (tid + 512) >> 3;  const int gc1 = (tid & 7) ^ (r1 & 7);
    const int wub = wid << 10;        // wave-uniform LDS byte base

    auto stageHalf = [&](int buf, int mat, int h, int kt) {
        const u16* src = mat ? Bt : A;
        const int base0 = mat ? n0 : m0;
        char* d = (char*)lds + buf * 65536 + mat * 32768 + h * 16384 + wub;
        gl_lds16(src + (size_t)(base0 + h * 128 + r0) * K + (kt << 6) + (gc0 << 3), d);
        gl_lds16(src + (size_t)(base0 + h * 128 + r1) * K + (kt << 6) + (gc1 << 3), d + 8192);
    };

    stageHalf(0, 0, 0, 0); stageHalf(0, 0, 1, 0);
    stageHalf(0, 1, 0, 0); stageHalf(0, 1, 1, 0);
    asm volatile("s_waitcnt vmcnt(0)" ::: "memory");
    __builtin_amdgcn_s_barrier();

    for (int t = 0; t < NT; ++t) {
        const int buf = t & 1, nbuf = buf ^ 1;
        const bool more = (t + 1 < NT);
        const int abase = buf * 65536 + wr * 16384;
        const int bbase = buf * 65536 + 32768 + (wc >> 1) * 16384;
        bf16x8 bfr[4][2];
        #pragma unroll
        for (int q = 0; q < 4; ++q) {
            bf16x8 afr[2][2];
            #pragma unroll
            for (int di = 0; di < 2; ++di)
                #pragma unroll
                for (int ks = 0; ks < 2; ++ks) {
                    int row = q * 32 + di * 16 + cl;
                    int gr = ks * 4 + g4;
                    afr[di][ks] = *(const bf16x8*)((char*)lds + abase + (((row << 3) + (gr ^ (row & 7))) << 4));
                }
            if (q == 0) {
                #pragma unroll
                for (int j = 0; j < 4; ++j)
                    #pragma unroll
                    for (int ks = 0; ks < 2; ++ks) {
                        int row = ((wc & 1) << 6) + j * 16 + cl;
                        int gr = ks * 4 + g4;
                        bfr[j][ks] = *(const bf16x8*)((char*)lds + bbase + (((row << 3) + (gr ^ (row & 7))) << 4));
                    }
                if (more) {   // R17: front-load ALL of tile t+1's staging (max latency cover)
                    stageHalf(nbuf, 0, 0, t + 1); stageHalf(nbuf, 0, 1, t + 1);
                    stageHalf(nbuf, 1, 0, t + 1); stageHalf(nbuf, 1, 1, t + 1);
                }
            }
            __builtin_amdgcn_s_barrier();
            asm volatile("s_waitcnt lgkmcnt(0)" ::: "memory");
            __builtin_amdgcn_sched_barrier(0);
            __builtin_amdgcn_s_setprio(1);
            #pragma unroll
            for (int di = 0; di < 2; ++di)
                #pragma unroll
                for (int j = 0; j < 4; ++j)
                    #pragma unroll
                    for (int ks = 0; ks < 2; ++ks)
                        acc[q * 2 + di][j] = __builtin_amdgcn_mfma_f32_16x16x32_bf16(
                            afr[di][ks], bfr[j][ks], acc[q * 2 + di][j], 0, 0, 0);
            __builtin_amdgcn_s_setprio(0);
            if (q == 3 && more) asm volatile("s_waitcnt vmcnt(0)" ::: "memory");
            __builtin_amdgcn_s_barrier();
            if (q == 3) __builtin_amdgcn_sched_barrier(0);
        }
    }
    #pragma unroll
    for (int i = 0; i < 8; ++i)
        #pragma unroll
        for (int j = 0; j < 4; ++j) {
            int row = m0 + wr * 128 + i * 16 + g4 * 4;
            int col = n0 + wc * 64 + j * 16 + cl;
            float bc = bias[col];
            #pragma unroll
            for (int rr = 0; rr < 4; ++rr) {
                float v = acc[i][j][rr] + bc;
                size_t idx = (size_t)(row + rr) * N + col;
                if constexpr (EPI == 0) {
                    outb[idx] = f2bfn(v);
                } else {
                    float tg = 0.7978845608f * (v + 0.044715f * v * v * v);
                    outb[idx] = f2bfn(v / (1.0f + exp2f(tg * -2.88539008f)));  // v*sigmoid(2t)
                }
            }
        }
}

// ---------------- gemm256r: gemm256 with split-K via grid.z (FFN2). Same R17 front-load.
// z == 0: out f32 = acc + bias + res.   z > 0: bf16 raw partial at poutb + (z-1)*M*N.
__global__ __launch_bounds__(512, 2) void gemm256r(const u16* __restrict__ A, const u16* __restrict__ Bt,
                                                   const float* __restrict__ bias,
                                                   const float* __restrict__ res,
                                                   float* __restrict__ outf, u16* __restrict__ poutb,
                                                   int M, int N, int K) {
    __shared__ __align__(16) u16 lds[65536];   // 128 KB
    const int tid = threadIdx.x;
    const int lane = tid & 63, wid = tid >> 6;
    const int cl = lane & 15, g4 = lane >> 4;
    const int wr = wid >> 2, wc = wid & 3;     // 2 x 4 wave grid
    const int gx = gridDim.x;
    const int lid = blockIdx.y * gx + blockIdx.x;
    const int per8 = (gx * gridDim.y) >> 3;
    const int newlin = (lid & 7) * per8 + (lid >> 3);
    const int m0 = (newlin / gx) << 8;
    const int n0 = (newlin % gx) << 8;
    const int kchunk = K / gridDim.z;
    const int kbase = blockIdx.z * kchunk;
    const int NT = kchunk >> 6;
    f32x4 acc[8][4] = {};
    const int r0 = tid >> 3;          const int gc0 = (tid & 7) ^ (r0 & 7);
    const int r1 = (tid + 512) >> 3;  const int gc1 = (tid & 7) ^ (r1 & 7);
    const int wub = wid << 10;

    auto stageHalf = [&](int buf, int mat, int h, int kt) {
        const u16* src = mat ? Bt : A;
        const int base0 = mat ? n0 : m0;
        char* d = (char*)lds + buf * 65536 + mat * 32768 + h * 16384 + wub;
        gl_lds16(src + (size_t)(base0 + h * 128 + r0) * K + kbase + (kt << 6) + (gc0 << 3), d);
        gl_lds16(src + (size_t)(base0 + h * 128 + r1) * K + kbase + (kt << 6) + (gc1 << 3), d + 8192);
    };

    stageHalf(0, 0, 0, 0); stageHalf(0, 0, 1, 0);
    stageHalf(0, 1, 0, 0); stageHalf(0, 1, 1, 0);
    asm volatile("s_waitcnt vmcnt(0)" ::: "memory");
    __builtin_amdgcn_s_barrier();

    for (int t = 0; t < NT; ++t) {
        const int buf = t & 1, nbuf = buf ^ 1;
        const bool more = (t + 1 < NT);
        const int abase = buf * 65536 + wr * 16384;
        const int bbase = buf * 65536 + 32768 + (wc >> 1) * 16384;
        bf16x8 bfr[4][2];
        #pragma unroll
        for (int q = 0; q < 4; ++q) {
            bf16x8 afr[2][2];
            #pragma unroll
            for (int di = 0; di < 2; ++di)
                #pragma unroll
                for (int ks = 0; ks < 2; ++ks) {
                    int row = q * 32 + di * 16 + cl;
                    int gr = ks * 4 + g4;
                    afr[di][ks] = *(const bf16x8*)((char*)lds + abase + (((row << 3) + (gr ^ (row & 7))) << 4));
                }
            if (q == 0) {
                #pragma unroll
                for (int j = 0; j < 4; ++j)
                    #pragma unroll
                    for (int ks = 0; ks < 2; ++ks) {
                        int row = ((wc & 1) << 6) + j * 16 + cl;
                        int gr = ks * 4 + g4;
                        bfr[j][ks] = *(const bf16x8*)((char*)lds + bbase + (((row << 3) + (gr ^ (row & 7))) << 4));
                    }
                if (more) {   // R17: front-load ALL of tile t+1's staging
                    stageHalf(nbuf, 0, 0, t + 1); stageHalf(nbuf, 0, 1, t + 1);
                    stageHalf(nbuf, 1, 0, t + 1); stageHalf(nbuf, 1, 1, t + 1);
                }
            }
            __builtin_amdgcn_s_barrier();
            asm volatile("s_waitcnt lgkmcnt(0)" ::: "memory");
            __builtin_amdgcn_sched_barrier(0);
            __builtin_amdgcn_s_setprio(1);
            #pragma unroll
            for (int di = 0; di < 2; ++di)
                #pragma unroll
                for (int j = 0; j < 4; ++j)
                    #pragma unroll
                    for (int ks = 0; ks < 2; ++ks)
                        acc[q * 2 + di][j] = __builtin_amdgcn_mfma_f32_16x16x32_bf16(
                            afr[di][ks], bfr[j][ks], acc[q * 2 + di][j], 0, 0, 0);
            __builtin_amdgcn_s_setprio(0);
            if (q == 3 && more) asm volatile("s_waitcnt vmcnt(0)" ::: "memory");
            __builtin_amdgcn_s_barrier();
            if (q == 3) __builtin_amdgcn_sched_barrier(0);
        }
    }
    if (blockIdx.z == 0) {
        #pragma unroll
        for (int i = 0; i < 8; ++i)
            #pragma unroll
            for (int j = 0; j < 4; ++j) {
                int row = m0 + wr * 128 + i * 16 + g4 * 4;
                int col = n0 + wc * 64 + j * 16 + cl;
                float bc = bias[col];
                #pragma unroll
                for (int rr = 0; rr < 4; ++rr) {
                    size_t idx = (size_t)(row + rr) * N + col;
                    outf[idx] = acc[i][j][rr] + bc + res[idx];
                }
            }
    } else {
        const size_t pbase = (size_t)(blockIdx.z - 1) * ((size_t)M * N);
        #pragma unroll
        for (int i = 0; i < 8; ++i)
            #pragma unroll
            for (int j = 0; j < 4; ++j) {
                int row = m0 + wr * 128 + i * 16 + g4 * 4;
                int col = n0 + wc * 64 + j * 16 + cl;
                #pragma unroll
                for (int rr = 0; rr < 4; ++rr)
                    poutb[pbase + (size_t)(row + rr) * N + col] = f2bfn(acc[i][j][rr]);
            }
    }
}

// ---------------- GEMM 128^2 (m97 + T1 + T4 + granule permute): used for wo
template <int EPI>
__global__ __launch_bounds__(256) void gemm_bt(const u16* __restrict__ A, const u16* __restrict__ Bt,
                                               const float* __restrict__ bias,
                                               const float* __restrict__ res,
                                               u16* __restrict__ outb, float* __restrict__ outf,
                                               u16* __restrict__ poutb,
                                               int M, int N, int K) {
    __shared__ __align__(16) u16 As[3][4096];
    __shared__ __align__(16) u16 Bs[3][4096];
    const int tid = threadIdx.x;
    const int lane = tid & 63, wid = tid >> 6;
    const int g = lane >> 4, cl = lane & 15;
    const int wr = wid >> 1, wc = wid & 1;
    const int gx = gridDim.x;
    const int lid = blockIdx.y * gx + blockIdx.x;
    const int per8 = (gx * gridDim.y) >> 3;
    const int newlin = (lid & 7) * per8 + (lid >> 3);
    const int m0 = (newlin / gx) << 7;
    const int n0 = (newlin % gx) << 7;
    const int kchunk = K / gridDim.z;
    const int kbase = blockIdx.z * kchunk;
    const int NT = kchunk >> 5;
    f32x4 acc[4][4] = {};
    const int grow = tid >> 2;
    const int gcol = (tid & 3) ^ ((tid >> 3) & 3);

    auto stage = [&](int buf, int kt) {
        const int ko = kbase + (kt << 5);
        gl_lds16(A + (size_t)(m0 + grow) * K + ko + (gcol << 3),       &As[buf][wid << 9]);
        gl_lds16(A + (size_t)(m0 + grow + 64) * K + ko + (gcol << 3),  &As[buf][(wid << 9) + 2048]);
        gl_lds16(Bt + (size_t)(n0 + grow) * K + ko + (gcol << 3),      &Bs[buf][wid << 9]);
        gl_lds16(Bt + (size_t)(n0 + grow + 64) * K + ko + (gcol << 3), &Bs[buf][(wid << 9) + 2048]);
    };

    stage(0, 0);
    stage(1, 1);
    for (int kt = 0; kt < NT; ++kt) {
        if (kt + 1 < NT) asm volatile("s_waitcnt vmcnt(4)" ::: "memory");
        else             asm volatile("s_waitcnt vmcnt(0)" ::: "memory");
        __builtin_amdgcn_s_barrier();
        __builtin_amdgcn_sched_barrier(0);
        if (kt + 2 < NT) stage((kt + 2) % 3, kt + 2);
        const int cb = kt % 3;
        bf16x8 a[4], b[4];
        #pragma unroll
        for (int i = 0; i < 4; ++i) {
            int row = (wr << 6) + (i << 4) + cl;
            a[i] = *(const bf16x8*)&As[cb][((row << 2) + (g ^ ((row >> 1) & 3))) << 3];
        }
        #pragma unroll
        for (int j = 0; j < 4; ++j) {
            int row = (wc << 6) + (j << 4) + cl;
            b[j] = *(const bf16x8*)&Bs[cb][((row << 2) + (g ^ ((row >> 1) & 3))) << 3];
        }
        __builtin_amdgcn_s_setprio(1);
        #pragma unroll
        for (int i = 0; i < 4; ++i)
            #pragma unroll
            for (int j = 0; j < 4; ++j)
                acc[i][j] = __builtin_amdgcn_mfma_f32_16x16x32_bf16(a[i], b[j], acc[i][j], 0, 0, 0);
        __builtin_amdgcn_s_setprio(0);
    }
    if (blockIdx.z == 0) {
        #pragma unroll
        for (int i = 0; i < 4; ++i)
            #pragma unroll
            for (int j = 0; j < 4; ++j) {
                int row = m0 + (wr << 6) + (i << 4) + (g << 2);
                int col = n0 + (wc << 6) + (j << 4) + cl;
                float bc = bias[col];
                #pragma unroll
                for (int rr = 0; rr < 4; ++rr) {
                    float v = acc[i][j][rr] + bc;
                    size_t idx = (size_t)(row + rr) * N + col;
                    outf[idx] = v + res[idx];
                }
            }
    } else {
        const size_t pbase = (size_t)(blockIdx.z - 1) * ((size_t)M * N);
        #pragma unroll
        for (int i = 0; i < 4; ++i)
            #pragma unroll
            for (int j = 0; j < 4; ++j) {
                int row = m0 + (wr << 6) + (i << 4) + (g << 2);
                int col = n0 + (wc << 6) + (j << 4) + cl;
                #pragma unroll
                for (int rr = 0; rr < 4; ++rr)
                    poutb[pbase + (size_t)(row + rr) * N + col] = f2bfn(acc[i][j][rr]);
            }
    }
}

// ---------------- split-K reduce: out += sum of bf16 partials (each 4096*1024 elements)
__global__ __launch_bounds__(256) void reduce_addb(float* __restrict__ out, const u16* __restrict__ p,
                                                   int nparts) {
    int i = blockIdx.x * 256 + threadIdx.x;   // x4 elements
    float4 a = ((const float4*)out)[i];
    for (int j = 0; j < nparts; ++j) {
        u16x4 v = *(const u16x4*)(p + (size_t)j * 4194304 + ((size_t)i << 2));
        a.x += bf2f(v[0]); a.y += bf2f(v[1]); a.z += bf2f(v[2]); a.w += bf2f(v[3]);
    }
    ((float4*)out)[i] = a;
}

// ---------------- RoPE for q,k: qkv[4096][3072] -> qr/kr [BH][S][64]
// q pre-scaled by 0.125 * log2(e) so attention uses exp2 directly
__global__ __launch_bounds__(256) void rope_qk(const u16* __restrict__ qkv,
                                               const float* __restrict__ cost,
                                               const float* __restrict__ sint,
                                               u16* __restrict__ qr, u16* __restrict__ kr) {
    int tid = threadIdx.x;
    int rowid = (blockIdx.x << 4) + (tid >> 4);  // bh*2048+s over [0,65536)
    int j = tid & 15;
    int half = j >> 3, jj = j & 7;
    int b = rowid >> 15;
    int h = (rowid >> 11) & 15;
    int s = rowid & 2047;
    size_t qbase = (size_t)((b << 11) + s) * 3072 + (h << 6);
    float cf[4], sf_[4];
    {
        float4 c = *(const float4*)(cost + (s << 5) + (jj << 2));
        float4 sn = *(const float4*)(sint + (s << 5) + (jj << 2));
        cf[0] = c.x; cf[1] = c.y; cf[2] = c.z; cf[3] = c.w;
        sf_[0] = sn.x; sf_[1] = sn.y; sf_[2] = sn.z; sf_[3] = sn.w;
    }
    size_t obase = (size_t)rowid * 64 + (half << 5) + (jj << 2);
    {
        u16x8 v = *(const u16x8*)(qkv + qbase + (jj << 3));
        u16x4 o;
        #pragma unroll
        for (int m2 = 0; m2 < 4; ++m2) {
            float e = bf2f(v[2 * m2]), od = bf2f(v[2 * m2 + 1]);
            float val = (half == 0) ? (e * cf[m2] - od * sf_[m2]) : (e * sf_[m2] + od * cf[m2]);
            o[m2] = f2bfn(val * 0.1803368801f);  // 0.125 * log2(e)
        }
        *(u16x4*)(qr + obase) = o;
    }
    {
        u16x8 v = *(const u16x8*)(qkv + qbase + 1024 + (jj << 3));
        u16x4 o;
        #pragma unroll
        for (int m2 = 0; m2 < 4; ++m2) {
            float e = bf2f(v[2 * m2]), od = bf2f(v[2 * m2 + 1]);
            float val = (half == 0) ? (e * cf[m2] - od * sf_[m2]) : (e * sf_[m2] + od * cf[m2]);
            o[m2] = f2bfn(val);
        }
        *(u16x4*)(kr + obase) = o;
    }
}

// ---------------- V transpose: qkv v-part -> vt[BH][64 d][2048 s]
__global__ __launch_bounds__(256) void v_transpose(const u16* __restrict__ qkv,
                                                   u16* __restrict__ vt) {
    __shared__ __align__(16) u16 tl[64 * 80];
    int stile = blockIdx.x, bh = blockIdx.y;
    int b = bh >> 4, h = bh & 15;
    int tid = threadIdx.x;
    #pragma unroll
    for (int i = 0; i < 2; ++i) {
        int slot = tid + (i << 8);
        int srow = slot >> 3, c = slot & 7;
        u16x8 v = *(const u16x8*)(qkv + (size_t)((b << 11) + (stile << 6) + srow) * 3072 + 2048 + (h << 6) + (c << 3));
        *(u16x8*)(tl + srow * 80 + (c << 3)) = v;
    }
    __syncthreads();
    #pragma unroll
    for (int i = 0; i < 2; ++i) {
        int slot = tid + (i << 8);
        int drow = slot >> 3, c = slot & 7;
        u16x8 o;
        #pragma unroll
        for (int m2 = 0; m2 < 8; ++m2) o[m2] = tl[(c * 8 + m2) * 80 + drow];
        *(u16x8*)(vt + ((size_t)bh * 64 + drow) * 2048 + (stile << 6) + (c << 3)) = o;
    }
}

// ---------------- flash attention (best-measured R12 config): triangle-paired blocks with XCD
// head affinity, reg-staged double-buffered K/V (T14 issue-early/write-late, 1 barrier/tile),
// swapped QK^T, float mask, cvt_pk P-pack.
__global__ __launch_bounds__(256) void attn_kernel(const u16* __restrict__ Q, const u16* __restrict__ Kd,
                                                   const u16* __restrict__ Vt, const float* __restrict__ maskf,
                                                   u16* __restrict__ ctx) {
    __shared__ __align__(16) u16 Ks[2][4096];
    __shared__ __align__(16) u16 Vs[2][4096];
    __shared__ __align__(16) u16 Ps[4096];
    const int tid = threadIdx.x, lane = tid & 63, w = tid >> 6;
    const int g = lane >> 4, cl = lane & 15;
    const int lid = blockIdx.y * 16 + blockIdx.x;   // grid (16,32) = 512 blocks
    const int xcd = lid & 7, slot = lid >> 3;       // slot in [0,64)
    const int bh = xcd * 4 + (slot >> 4);           // 4 heads per XCD (K/V L2-resident)
    const int pair = slot & 15;                     // 16 pair-blocks per head
    const int b = bh >> 4, h = bh & 15;
    const u16* Kb = Kd + (size_t)bh * 2048 * 64;
    const u16* Vb = Vt + (size_t)bh * 64 * 2048;
    const int srow0 = tid >> 3, sc0 = tid & 7;
    const int srow1 = (tid + 256) >> 3, sc1 = sc0;
    bf16x8 onesb;
    #pragma unroll
    for (int i2 = 0; i2 < 8; ++i2) onesb[i2] = (__bf16)1.0f;
    // P write base: row = q = cl, 8B slot for (ct,g) at granule (ct*2+(g>>1)) ^ (cl&7)
    char* const pwb = (char*)Ps + w * 2048 + cl * 128 + ((g & 1) << 3);

    #pragma unroll
    for (int ci = 0; ci < 2; ++ci) {
        const int qb = (ci == 0) ? (31 - pair) : pair;  // heavy chunk first
        const size_t qoff = ((size_t)bh * 2048 + qb * 64 + w * 16 + cl) * 64;
        const bf16x8 qa0 = *(const bf16x8*)(Q + qoff + (g << 3));
        const bf16x8 qa1 = *(const bf16x8*)(Q + qoff + 32 + (g << 3));
        const int qrow = qb * 64 + w * 16 + cl;     // this lane's q row (S^T layout)
        f32x4 acc[4] = {};
        f32x4 lsum = {};

        u16x8 k0a = *(const u16x8*)(Kb + (size_t)srow0 * 64 + (sc0 << 3));
        u16x8 k0b = *(const u16x8*)(Kb + (size_t)srow1 * 64 + (sc1 << 3));
        u16x8 v0a = *(const u16x8*)(Vb + (size_t)srow0 * 2048 + (sc0 << 3));
        u16x8 v0b = *(const u16x8*)(Vb + (size_t)srow1 * 2048 + (sc1 << 3));
        __syncthreads();  // previous chunk's LDS readers done
        *(u16x8*)((char*)&Ks[0][0] + srow0 * 128 + ((sc0 ^ (srow0 & 7)) << 4)) = k0a;
        *(u16x8*)((char*)&Ks[0][0] + srow1 * 128 + ((sc1 ^ (srow1 & 7)) << 4)) = k0b;
        *(u16x8*)((char*)&Vs[0][0] + srow0 * 128 + ((sc0 ^ (srow0 & 7)) << 4)) = v0a;
        *(u16x8*)((char*)&Vs[0][0] + srow1 * 128 + ((sc1 ^ (srow1 & 7)) << 4)) = v0b;
        __syncthreads();

        int cur = 0;
        for (int t = 0; t <= qb; ++t) {
            const bool more = (t < qb);
            u16x8 rka, rkb, rva, rvb;
            if (more) {
                const u16* Kg = Kb + (size_t)(t + 1) * 64 * 64;
                rka = *(const u16x8*)(Kg + (size_t)srow0 * 64 + (sc0 << 3));
                rkb = *(const u16x8*)(Kg + (size_t)srow1 * 64 + (sc1 << 3));
                rva = *(const u16x8*)(Vb + (size_t)srow0 * 2048 + (t + 1) * 64 + (sc0 << 3));
                rvb = *(const u16x8*)(Vb + (size_t)srow1 * 2048 + (t + 1) * 64 + (sc1 << 3));
            }
            // swapped QK^T: sf[ct][rr] = S[q = qrow][k = t*64 + ct*16 + g*4 + rr]
            f32x4 sf[4];
            __builtin_amdgcn_s_setprio(1);
            #pragma unroll
            for (int ct = 0; ct < 4; ++ct) {
                f32x4 s = {};
                int krow = ct * 16 + cl;
                bf16x8 kb0 = *(const bf16x8*)((char*)&Ks[cur][0] + krow * 128 + ((g ^ (krow & 7)) << 4));
                bf16x8 kb1 = *(const bf16x8*)((char*)&Ks[cur][0] + krow * 128 + (((4 + g) ^ (krow & 7)) << 4));
                s = __builtin_amdgcn_mfma_f32_16x16x32_bf16(kb0, qa0, s, 0, 0, 0);
                s = __builtin_amdgcn_mfma_f32_16x16x32_bf16(kb1, qa1, s, 0, 0, 0);
                sf[ct] = s;
            }
            __builtin_amdgcn_s_setprio(0);
            // p = exp2(s) * mask * causal; pack 4 consecutive k as 2 cvt_pk -> one 8B write
            const bool diag = (t == qb);
            #pragma unroll
            for (int ct = 0; ct < 4; ++ct) {
                const int kc0 = t * 64 + ct * 16 + (g << 2);
                const float4 mv = *(const float4*)(maskf + (b << 11) + kc0);
                float p0 = exp2f(sf[ct][0]) * mv.x;
                float p1 = exp2f(sf[ct][1]) * mv.y;
                float p2 = exp2f(sf[ct][2]) * mv.z;
                float p3 = exp2f(sf[ct][3]) * mv.w;
                if (diag) {
                    p0 = (kc0 + 0 <= qrow) ? p0 : 0.0f;
                    p1 = (kc0 + 1 <= qrow) ? p1 : 0.0f;
                    p2 = (kc0 + 2 <= qrow) ? p2 : 0.0f;
                    p3 = (kc0 + 3 <= qrow) ? p3 : 0.0f;
                }
                u32 lo, hi;
                asm("v_cvt_pk_bf16_f32 %0, %1, %2" : "=v"(lo) : "v"(p0), "v"(p1));
                asm("v_cvt_pk_bf16_f32 %0, %1, %2" : "=v"(hi) : "v"(p2), "v"(p3));
                uint2 pk; pk.x = lo; pk.y = hi;
                *(uint2*)(pwb + ((((ct << 1) + (g >> 1)) ^ (cl & 7)) << 4)) = pk;
            }
            // PV + row-sum (ones-MFMA) from buf[cur]
            __builtin_amdgcn_s_setprio(1);
            #pragma unroll
            for (int kc = 0; kc < 2; ++kc) {
                bf16x8 pa = *(const bf16x8*)((char*)Ps + w * 2048 + cl * 128 + (((kc * 4 + g) ^ (cl & 7)) << 4));
                lsum = __builtin_amdgcn_mfma_f32_16x16x32_bf16(pa, onesb, lsum, 0, 0, 0);
                #pragma unroll
                for (int n = 0; n < 4; ++n) {
                    int vrow = n * 16 + cl;
                    bf16x8 vb = *(const bf16x8*)((char*)&Vs[cur][0] + vrow * 128 + (((kc * 4 + g) ^ (vrow & 7)) << 4));
                    acc[n] = __builtin_amdgcn_mfma_f32_16x16x32_bf16(pa, vb, acc[n], 0, 0, 0);
                }
            }
            __builtin_amdgcn_s_setprio(0);
            if (more) {
                *(u16x8*)((char*)&Ks[cur ^ 1][0] + srow0 * 128 + ((sc0 ^ (srow0 & 7)) << 4)) = rka;
                *(u16x8*)((char*)&Ks[cur ^ 1][0] + srow1 * 128 + ((sc1 ^ (srow1 & 7)) << 4)) = rkb;
                *(u16x8*)((char*)&Vs[cur ^ 1][0] + srow0 * 128 + ((sc0 ^ (srow0 & 7)) << 4)) = rva;
                *(u16x8*)((char*)&Vs[cur ^ 1][0] + srow1 * 128 + ((sc1 ^ (srow1 & 7)) << 4)) = rvb;
                __syncthreads();
            }
            cur ^= 1;
        }
        #pragma unroll
        for (int n = 0; n < 4; ++n)
            #pragma unroll
            for (int rr = 0; rr < 4; ++rr) {
                int token = (b << 11) + qb * 64 + w * 16 + g * 4 + rr;
                int col = (h << 6) + n * 16 + cl;
                ctx[(size_t)token * 1024 + col] = f2bfn(acc[n][rr] / lsum[rr]);
            }
    }
}

extern "C" void kernel_launch(void* const* d_in, const int* in_sizes, int n_in,
                              void* d_out, int out_size, void* d_ws, size_t ws_size,
                              hipStream_t stream) {
    const float* x   = (const float*)d_in[0];
    const int* mask  = (const int*)d_in[1];
    const float* wq  = (const float*)d_in[2];
    const float* bq  = (const float*)d_in[3];
    const float* wk  = (const float*)d_in[4];
    const float* bk  = (const float*)d_in[5];
    const float* wv  = (const float*)d_in[6];
    const float* bv  = (const float*)d_in[7];
    const float* wo  = (const float*)d_in[8];
    const float* bo  = (const float*)d_in[9];
    const float* w1  = (const float*)d_in[10];
    const float* b1  = (const float*)d_in[11];
    const float* w2  = (const float*)d_in[12];
    const float* b2  = (const float*)d_in[13];
    const float* g1  = (const float*)d_in[14];
    const float* be1 = (const float*)d_in[15];
    const float* g2  = (const float*)d_in[16];
    const float* be2 = (const float*)d_in[17];
    float* out = (float*)d_out;
    char* ws = (char*)d_ws;

    // ws map (109.59 MB total, overlays noted):
    u16* wqkvT  = (u16*)(ws + 0);            //  6 MB, whole call
    u16* woT    = (u16*)(ws + 6291456);      //  2 MB
    u16* w1T    = (u16*)(ws + 8388608);      //  8 MB
    u16* w2T    = (u16*)(ws + 16777216);     //  8 MB
    float* bqkv = (float*)(ws + 25165824);   // 12 KB
    float* cost = (float*)(ws + 25178112);   // 256 KB
    float* sint = (float*)(ws + 25440256);   // 256 KB
    u16* xn     = (u16*)(ws + 25702400);     //  8 MB (LN1 out; reused for LN2 out)
    float* x2   = (float*)(ws + 34091008);   // 16 MB (residual-2 base; first written by wo-gemm)
    float* maskf= (float*)(ws + 34091008);   // 16 KB overlay on x2 head (dead once wo-gemm writes x2)
    u16* qkv    = (u16*)(ws + 50868224);     // 24 MB (dead after v_transpose)
    u16* ffh    = (u16*)(ws + 50868224);     // 32 MB overlay on qkv+qr; spans to 84422656
    u16* qr     = (u16*)(ws + 76034048);     //  8 MB (dead after attn)
    u16* kr     = (u16*)(ws + 84422656);     //  8 MB (dead after attn)
    u16* vt     = (u16*)(ws + 92811264);     //  8 MB (dead after attn)
    u16* ctx    = (u16*)(ws + 101199872);    //  8 MB (dead after wo-gemm)
    // bf16 split-K partials: 3 x 8 MB on kr+vt+ctx. DISJOINT from ffh (ends 84422656).
    u16* partb  = (u16*)(ws + 84422656);

    transpose_cvt4<<<dim3(32, 32, 4), 256, 0, stream>>>(wq, wk, wv, wo,
                                                        wqkvT, wqkvT + 1024 * 1024, wqkvT + 2048 * 1024, woT);
    transpose_cvt2<<<dim3(128, 32, 2), 256, 0, stream>>>(w1, w2, w1T, w2T);
    prep_kernel<<<256, 256, 0, stream>>>(bq, bk, bv, bqkv, mask, maskf, cost, sint);

    ln_kernel<<<4096, 256, 0, stream>>>(x, g1, be1, xn);
    gemm256<0><<<dim3(12, 16), 512, 0, stream>>>(xn, wqkvT, bqkv, qkv, 4096, 3072, 1024);
    rope_qk<<<4096, 256, 0, stream>>>(qkv, cost, sint, qr, kr);
    v_transpose<<<dim3(32, 32), 256, 0, stream>>>(qkv, vt);
    attn_kernel<<<dim3(16, 32), 256, 0, stream>>>(qr, kr, vt, maskf, ctx);
    gemm_bt<1><<<dim3(8, 32, 2), 256, 0, stream>>>(ctx, woT, bo, x, nullptr, x2, partb, 4096, 1024, 1024);
    ln_fuse<<<4096, 256, 0, stream>>>(x2, partb, g2, be2, xn);
    gemm256<2><<<dim3(16, 16), 512, 0, stream>>>(xn, w1T, b1, ffh, 4096, 4096, 1024);
    gemm256r<<<dim3(4, 16, 4), 512, 0, stream>>>(ffh, w2T, b2, x2, out, partb, 4096, 1024, 4096);
    reduce_addb<<<4096, 256, 0, stream>>>(out, partb, 3);
}

// Round 18
// 235.564 us; speedup vs baseline: 1.3711x; 1.0196x over previous
//
#include <hip/hip_runtime.h>

typedef unsigned short u16;
typedef unsigned int u32;
typedef __attribute__((ext_vector_type(8))) u16 u16x8;
typedef __attribute__((ext_vector_type(4))) u16 u16x4;
typedef __attribute__((ext_vector_type(8))) __bf16 bf16x8;
typedef __attribute__((ext_vector_type(4))) float f32x4;

static __device__ __forceinline__ float bf2f(u16 u) {
    union { u32 i; float f; } v; v.i = ((u32)u) << 16; return v.f;
}
static __device__ __forceinline__ u16 f2bf(float f) {   // manual RNE (cold paths)
    union { float f; u32 i; } v; v.f = f;
    u32 r = v.i + 0x7fffu + ((v.i >> 16) & 1u);
    return (u16)(r >> 16);
}
static __device__ __forceinline__ u16 f2bfn(float f) {  // native cvt (hot paths)
    __bf16 h = (__bf16)f;
    return *(u16*)&h;
}
// async global -> LDS, 16B per lane; ldst must be wave-uniform (HW adds lane*16)
static __device__ __forceinline__ void gl_lds16(const void* gsrc, void* ldst) {
    __builtin_amdgcn_global_load_lds((const __attribute__((address_space(1))) void*)gsrc,
                                     (__attribute__((address_space(3))) void*)ldst, 16, 0, 0);
}

// ---------------- weight transpose + fp32->bf16 convert: out[n][k] = in[k][n]
// batched 1024x1024 variant: z selects (wq,wk,wv,wo)
__global__ __launch_bounds__(256) void transpose_cvt4(const float* __restrict__ w0, const float* __restrict__ w1,
                                                      const float* __restrict__ w2, const float* __restrict__ w3,
                                                      u16* __restrict__ o0, u16* __restrict__ o1,
                                                      u16* __restrict__ o2, u16* __restrict__ o3) {
    __shared__ float t[32][33];
    const float* in; u16* out;
    switch (blockIdx.z) {
        case 0:  in = w0; out = o0; break;
        case 1:  in = w1; out = o1; break;
        case 2:  in = w2; out = o2; break;
        default: in = w3; out = o3; break;
    }
    int k0 = blockIdx.y << 5, n0 = blockIdx.x << 5;
    int r = threadIdx.x >> 3, c4 = threadIdx.x & 7;
    float4 v = *(const float4*)(in + (size_t)(k0 + r) * 1024 + n0 + (c4 << 2));
    t[r][c4 * 4 + 0] = v.x; t[r][c4 * 4 + 1] = v.y;
    t[r][c4 * 4 + 2] = v.z; t[r][c4 * 4 + 3] = v.w;
    __syncthreads();
    u16x4 o;
    o[0] = f2bf(t[c4 * 4 + 0][r]); o[1] = f2bf(t[c4 * 4 + 1][r]);
    o[2] = f2bf(t[c4 * 4 + 2][r]); o[3] = f2bf(t[c4 * 4 + 3][r]);
    *(u16x4*)(out + (size_t)(n0 + r) * 1024 + k0 + (c4 << 2)) = o;
}

// w1 (1024x4096) and w2 (4096x1024) in one launch: grid (128, 32, 2)
__global__ __launch_bounds__(256) void transpose_cvt2(const float* __restrict__ w1, const float* __restrict__ w2,
                                                      u16* __restrict__ o1, u16* __restrict__ o2) {
    __shared__ float t[32][33];
    const int zz = blockIdx.z;
    const float* in = zz ? w2 : w1;
    u16* out = zz ? o2 : o1;
    const int K = zz ? 4096 : 1024, N = zz ? 1024 : 4096;
    int k0, n0;
    if (zz) { k0 = blockIdx.x << 5; n0 = blockIdx.y << 5; }
    else    { n0 = blockIdx.x << 5; k0 = blockIdx.y << 5; }
    int r = threadIdx.x >> 3, c4 = threadIdx.x & 7;
    float4 v = *(const float4*)(in + (size_t)(k0 + r) * N + n0 + (c4 << 2));
    t[r][c4 * 4 + 0] = v.x; t[r][c4 * 4 + 1] = v.y;
    t[r][c4 * 4 + 2] = v.z; t[r][c4 * 4 + 3] = v.w;
    __syncthreads();
    u16x4 o;
    o[0] = f2bf(t[c4 * 4 + 0][r]); o[1] = f2bf(t[c4 * 4 + 1][r]);
    o[2] = f2bf(t[c4 * 4 + 2][r]); o[3] = f2bf(t[c4 * 4 + 3][r]);
    *(u16x4*)(out + (size_t)(n0 + r) * K + k0 + (c4 << 2)) = o;
}

// ---------------- prep: rope table + qkv bias concat + float mask (one launch, grid 256x256)
__global__ void prep_kernel(const float* __restrict__ bq, const float* __restrict__ bk,
                            const float* __restrict__ bv, float* __restrict__ bqkv,
                            const int* __restrict__ mask, float* __restrict__ maskf,
                            float* __restrict__ cost, float* __restrict__ sint) {
    int idx = blockIdx.x * 256 + threadIdx.x;  // 65536 = 2048 * 32
    int s = idx >> 5, f = idx & 31;
    float inv = powf(10000.0f, -((float)(2 * f)) / 64.0f);
    float a = (float)s * inv;
    cost[idx] = cosf(a);
    sint[idx] = sinf(a);
    if (idx < 3072) {
        float v = (idx < 1024) ? bq[idx] : (idx < 2048 ? bk[idx - 1024] : bv[idx - 2048]);
        bqkv[idx] = v;
    }
    if (idx < 4096) maskf[idx] = (float)mask[idx];
}

// ---------------- LayerNorm: 1 block / row of 1024, output bf16
__global__ __launch_bounds__(256) void ln_kernel(const float* __restrict__ x,
                                                 const float* __restrict__ gam,
                                                 const float* __restrict__ bet,
                                                 u16* __restrict__ out) {
    int row = blockIdx.x, tid = threadIdx.x;
    float4 v = *((const float4*)(x + (size_t)row * 1024) + tid);
    float s = v.x + v.y + v.z + v.w;
    float sq = v.x * v.x + v.y * v.y + v.z * v.z + v.w * v.w;
    #pragma unroll
    for (int off = 32; off >= 1; off >>= 1) {
        s += __shfl_xor(s, off);
        sq += __shfl_xor(sq, off);
    }
    __shared__ float red[8];
    int wid = tid >> 6, lane = tid & 63;
    if (lane == 0) { red[wid] = s; red[wid + 4] = sq; }
    __syncthreads();
    float ts = red[0] + red[1] + red[2] + red[3];
    float tq = red[4] + red[5] + red[6] + red[7];
    float mean = ts * (1.0f / 1024.0f);
    float var = tq * (1.0f / 1024.0f) - mean * mean;
    float rstd = rsqrtf(var + 1e-5f);
    float4 g = ((const float4*)gam)[tid];
    float4 b = ((const float4*)bet)[tid];
    u16x4 o;
    o[0] = f2bfn((v.x - mean) * rstd * g.x + b.x);
    o[1] = f2bfn((v.y - mean) * rstd * g.y + b.y);
    o[2] = f2bfn((v.z - mean) * rstd * g.z + b.z);
    o[3] = f2bfn((v.w - mean) * rstd * g.w + b.w);
    *(u16x4*)(out + (size_t)row * 1024 + (tid << 2)) = o;
}

// ---------------- LN2 fused with wo split-K merge: x2 += bf16 partial; xn = LN(x2)
__global__ __launch_bounds__(256) void ln_fuse(float* __restrict__ x2, const u16* __restrict__ part,
                                               const float* __restrict__ gam, const float* __restrict__ bet,
                                               u16* __restrict__ out) {
    int row = blockIdx.x, tid = threadIdx.x;
    float4 v = *((const float4*)(x2 + (size_t)row * 1024) + tid);
    u16x4 pv = *(const u16x4*)(part + (size_t)row * 1024 + (tid << 2));
    v.x += bf2f(pv[0]); v.y += bf2f(pv[1]); v.z += bf2f(pv[2]); v.w += bf2f(pv[3]);
    *((float4*)(x2 + (size_t)row * 1024) + tid) = v;   // residual base for FFN2
    float s = v.x + v.y + v.z + v.w;
    float sq = v.x * v.x + v.y * v.y + v.z * v.z + v.w * v.w;
    #pragma unroll
    for (int off = 32; off >= 1; off >>= 1) {
        s += __shfl_xor(s, off);
        sq += __shfl_xor(sq, off);
    }
    __shared__ float red[8];
    int wid = tid >> 6, lane = tid & 63;
    if (lane == 0) { red[wid] = s; red[wid + 4] = sq; }
    __syncthreads();
    float ts = red[0] + red[1] + red[2] + red[3];
    float tq = red[4] + red[5] + red[6] + red[7];
    float mean = ts * (1.0f / 1024.0f);
    float var = tq * (1.0f / 1024.0f) - mean * mean;
    float rstd = rsqrtf(var + 1e-5f);
    float4 g = ((const float4*)gam)[tid];
    float4 b = ((const float4*)bet)[tid];
    u16x4 o;
    o[0] = f2bfn((v.x - mean) * rstd * g.x + b.x);
    o[1] = f2bfn((v.y - mean) * rstd * g.y + b.y);
    o[2] = f2bfn((v.z - mean) * rstd * g.z + b.z);
    o[3] = f2bfn((v.w - mean) * rstd * g.w + b.w);
    *(u16x4*)(out + (size_t)row * 1024 + (tid << 2)) = o;
}

// ---------------- gemm256: 256x256 tile, BK=64, 8 waves (2Mx4N), phased schedule.
// R18 (T4 counted vmcnt): tile t+1 staging staggered q0:B(4), q1:A-h0(2), q2:A-h1(2).
// Boundary waits vmcnt(2) (A-h1 stays in flight across the barrier); q1-end waits vmcnt(6)
// so phase 2's A-h1(t) read is safe. Loads never drain to 0 mid-loop. Per-wave vmcnt +
// barrier = collective guarantee (gl_lds16 slices are wave-disjoint).
// EPI 0: out bf16 = acc+bias      EPI 2: out bf16 = gelu(acc+bias)
template <int EPI>
__global__ __launch_bounds__(512, 2) void gemm256(const u16* __restrict__ A, const u16* __restrict__ Bt,
                                                  const float* __restrict__ bias,
                                                  u16* __restrict__ outb, int M, int N, int K) {
    __shared__ __align__(16) u16 lds[65536];   // 128 KB
    const int tid = threadIdx.x;
    const int lane = tid & 63, wid = tid >> 6;
    const int cl = lane & 15, g4 = lane >> 4;
    const int wr = wid >> 2, wc = wid & 3;     // 2 x 4 wave grid
    const int gx = gridDim.x;
    const int lid = blockIdx.y * gx + blockIdx.x;
    const int per8 = (gx * gridDim.y) >> 3;
    const int newlin = (lid & 7) * per8 + (lid >> 3);
    const int m0 = (newlin / gx) << 8;
    const int n0 = (newlin % gx) << 8;
    const int NT = K >> 6;
    f32x4 acc[8][4] = {};
    const int r0 = tid >> 3;          const int gc0 = (tid & 7) ^ (r0 & 7);
    const int r1 = (tid + 512) >> 3;  const int gc1 = (tid & 7) ^ (r1 & 7);
    const int wub = wid << 10;        // wave-uniform LDS byte base

    auto stageHalf = [&](int buf, int mat, int h, int kt) {   // 2 vmem per wave
        const u16* src = mat ? Bt : A;
        const int base0 = mat ? n0 : m0;
        char* d = (char*)lds + buf * 65536 + mat * 32768 + h * 16384 + wub;
        gl_lds16(src + (size_t)(base0 + h * 128 + r0) * K + (kt << 6) + (gc0 << 3), d);
        gl_lds16(src + (size_t)(base0 + h * 128 + r1) * K + (kt << 6) + (gc1 << 3), d + 8192);
    };

    // prologue: B first, then A (phase 0 needs B + A-h0 -> oldest 6 loads)
    stageHalf(0, 1, 0, 0); stageHalf(0, 1, 1, 0);
    stageHalf(0, 0, 0, 0); stageHalf(0, 0, 1, 0);
    asm volatile("s_waitcnt vmcnt(2)" ::: "memory");
    __builtin_amdgcn_s_barrier();

    for (int t = 0; t < NT; ++t) {
        const int buf = t & 1, nbuf = buf ^ 1;
        const bool more = (t + 1 < NT);
        const int abase = buf * 65536 + wr * 16384;
        const int bbase = buf * 65536 + 32768 + (wc >> 1) * 16384;
        bf16x8 bfr[4][2];
        #pragma unroll
        for (int q = 0; q < 4; ++q) {
            bf16x8 afr[2][2];
            #pragma unroll
            for (int di = 0; di < 2; ++di)
                #pragma unroll
                for (int ks = 0; ks < 2; ++ks) {
                    int row = q * 32 + di * 16 + cl;
                    int gr = ks * 4 + g4;
                    afr[di][ks] = *(const bf16x8*)((char*)lds + abase + (((row << 3) + (gr ^ (row & 7))) << 4));
                }
            if (q == 0) {
                #pragma unroll
                for (int j = 0; j < 4; ++j)
                    #pragma unroll
                    for (int ks = 0; ks < 2; ++ks) {
                        int row = ((wc & 1) << 6) + j * 16 + cl;
                        int gr = ks * 4 + g4;
                        bfr[j][ks] = *(const bf16x8*)((char*)lds + bbase + (((row << 3) + (gr ^ (row & 7))) << 4));
                    }
                if (more) { stageHalf(nbuf, 1, 0, t + 1); stageHalf(nbuf, 1, 1, t + 1); }  // B(t+1)
            }
            if (q == 1 && more) stageHalf(nbuf, 0, 0, t + 1);   // A-h0(t+1)
            if (q == 2 && more) stageHalf(nbuf, 0, 1, t + 1);   // A-h1(t+1)
            __builtin_amdgcn_s_barrier();
            asm volatile("s_waitcnt lgkmcnt(0)" ::: "memory");
            __builtin_amdgcn_sched_barrier(0);
            __builtin_amdgcn_s_setprio(1);
            #pragma unroll
            for (int di = 0; di < 2; ++di)
                #pragma unroll
                for (int j = 0; j < 4; ++j)
                    #pragma unroll
                    for (int ks = 0; ks < 2; ++ks)
                        acc[q * 2 + di][j] = __builtin_amdgcn_mfma_f32_16x16x32_bf16(
                            afr[di][ks], bfr[j][ks], acc[q * 2 + di][j], 0, 0, 0);
            __builtin_amdgcn_s_setprio(0);
            if (q == 1) {   // phase 2 reads A-h1(t): wait its 2 loads (oldest of 8 outstanding)
                if (more) asm volatile("s_waitcnt vmcnt(6)" ::: "memory");
                else      asm volatile("s_waitcnt vmcnt(0)" ::: "memory");
            }
            if (q == 3 && more) asm volatile("s_waitcnt vmcnt(2)" ::: "memory");  // B+A-h0(t+1) ready
            __builtin_amdgcn_s_barrier();
            if (q == 3) __builtin_amdgcn_sched_barrier(0);
        }
    }
    #pragma unroll
    for (int i = 0; i < 8; ++i)
        #pragma unroll
        for (int j = 0; j < 4; ++j) {
            int row = m0 + wr * 128 + i * 16 + g4 * 4;
            int col = n0 + wc * 64 + j * 16 + cl;
            float bc = bias[col];
            #pragma unroll
            for (int rr = 0; rr < 4; ++rr) {
                float v = acc[i][j][rr] + bc;
                size_t idx = (size_t)(row + rr) * N + col;
                if constexpr (EPI == 0) {
                    outb[idx] = f2bfn(v);
                } else {
                    float tg = 0.7978845608f * (v + 0.044715f * v * v * v);
                    outb[idx] = f2bfn(v / (1.0f + exp2f(tg * -2.88539008f)));  // v*sigmoid(2t)
                }
            }
        }
}

// ---------------- gemm256r: gemm256 with split-K via grid.z (FFN2). Same R18 counted vmcnt.
// z == 0: out f32 = acc + bias + res.   z > 0: bf16 raw partial at poutb + (z-1)*M*N.
__global__ __launch_bounds__(512, 2) void gemm256r(const u16* __restrict__ A, const u16* __restrict__ Bt,
                                                   const float* __restrict__ bias,
                                                   const float* __restrict__ res,
                                                   float* __restrict__ outf, u16* __restrict__ poutb,
                                                   int M, int N, int K) {
    __shared__ __align__(16) u16 lds[65536];   // 128 KB
    const int tid = threadIdx.x;
    const int lane = tid & 63, wid = tid >> 6;
    const int cl = lane & 15, g4 = lane >> 4;
    const int wr = wid >> 2, wc = wid & 3;     // 2 x 4 wave grid
    const int gx = gridDim.x;
    const int lid = blockIdx.y * gx + blockIdx.x;
    const int per8 = (gx * gridDim.y) >> 3;
    const int newlin = (lid & 7) * per8 + (lid >> 3);
    const int m0 = (newlin / gx) << 8;
    const int n0 = (newlin % gx) << 8;
    const int kchunk = K / gridDim.z;
    const int kbase = blockIdx.z * kchunk;
    const int NT = kchunk >> 6;
    f32x4 acc[8][4] = {};
    const int r0 = tid >> 3;          const int gc0 = (tid & 7) ^ (r0 & 7);
    const int r1 = (tid + 512) >> 3;  const int gc1 = (tid & 7) ^ (r1 & 7);
    const int wub = wid << 10;

    auto stageHalf = [&](int buf, int mat, int h, int kt) {
        const u16* src = mat ? Bt : A;
        const int base0 = mat ? n0 : m0;
        char* d = (char*)lds + buf * 65536 + mat * 32768 + h * 16384 + wub;
        gl_lds16(src + (size_t)(base0 + h * 128 + r0) * K + kbase + (kt << 6) + (gc0 << 3), d);
        gl_lds16(src + (size_t)(base0 + h * 128 + r1) * K + kbase + (kt << 6) + (gc1 << 3), d + 8192);
    };

    stageHalf(0, 1, 0, 0); stageHalf(0, 1, 1, 0);
    stageHalf(0, 0, 0, 0); stageHalf(0, 0, 1, 0);
    asm volatile("s_waitcnt vmcnt(2)" ::: "memory");
    __builtin_amdgcn_s_barrier();

    for (int t = 0; t < NT; ++t) {
        const int buf = t & 1, nbuf = buf ^ 1;
        const bool more = (t + 1 < NT);
        const int abase = buf * 65536 + wr * 16384;
        const int bbase = buf * 65536 + 32768 + (wc >> 1) * 16384;
        bf16x8 bfr[4][2];
        #pragma unroll
        for (int q = 0; q < 4; ++q) {
            bf16x8 afr[2][2];
            #pragma unroll
            for (int di = 0; di < 2; ++di)
                #pragma unroll
                for (int ks = 0; ks < 2; ++ks) {
                    int row = q * 32 + di * 16 + cl;
                    int gr = ks * 4 + g4;
                    afr[di][ks] = *(const bf16x8*)((char*)lds + abase + (((row << 3) + (gr ^ (row & 7))) << 4));
                }
            if (q == 0) {
                #pragma unroll
                for (int j = 0; j < 4; ++j)
                    #pragma unroll
                    for (int ks = 0; ks < 2; ++ks) {
                        int row = ((wc & 1) << 6) + j * 16 + cl;
                        int gr = ks * 4 + g4;
                        bfr[j][ks] = *(const bf16x8*)((char*)lds + bbase + (((row << 3) + (gr ^ (row & 7))) << 4));
                    }
                if (more) { stageHalf(nbuf, 1, 0, t + 1); stageHalf(nbuf, 1, 1, t + 1); }
            }
            if (q == 1 && more) stageHalf(nbuf, 0, 0, t + 1);
            if (q == 2 && more) stageHalf(nbuf, 0, 1, t + 1);
            __builtin_amdgcn_s_barrier();
            asm volatile("s_waitcnt lgkmcnt(0)" ::: "memory");
            __builtin_amdgcn_sched_barrier(0);
            __builtin_amdgcn_s_setprio(1);
            #pragma unroll
            for (int di = 0; di < 2; ++di)
                #pragma unroll
                for (int j = 0; j < 4; ++j)
                    #pragma unroll
                    for (int ks = 0; ks < 2; ++ks)
                        acc[q * 2 + di][j] = __builtin_amdgcn_mfma_f32_16x16x32_bf16(
                            afr[di][ks], bfr[j][ks], acc[q * 2 + di][j], 0, 0, 0);
            __builtin_amdgcn_s_setprio(0);
            if (q == 1) {
                if (more) asm volatile("s_waitcnt vmcnt(6)" ::: "memory");
                else      asm volatile("s_waitcnt vmcnt(0)" ::: "memory");
            }
            if (q == 3 && more) asm volatile("s_waitcnt vmcnt(2)" ::: "memory");
            __builtin_amdgcn_s_barrier();
            if (q == 3) __builtin_amdgcn_sched_barrier(0);
        }
    }
    if (blockIdx.z == 0) {
        #pragma unroll
        for (int i = 0; i < 8; ++i)
            #pragma unroll
            for (int j = 0; j < 4; ++j) {
                int row = m0 + wr * 128 + i * 16 + g4 * 4;
                int col = n0 + wc * 64 + j * 16 + cl;
                float bc = bias[col];
                #pragma unroll
                for (int rr = 0; rr < 4; ++rr) {
                    size_t idx = (size_t)(row + rr) * N + col;
                    outf[idx] = acc[i][j][rr] + bc + res[idx];
                }
            }
    } else {
        const size_t pbase = (size_t)(blockIdx.z - 1) * ((size_t)M * N);
        #pragma unroll
        for (int i = 0; i < 8; ++i)
            #pragma unroll
            for (int j = 0; j < 4; ++j) {
                int row = m0 + wr * 128 + i * 16 + g4 * 4;
                int col = n0 + wc * 64 + j * 16 + cl;
                #pragma unroll
                for (int rr = 0; rr < 4; ++rr)
                    poutb[pbase + (size_t)(row + rr) * N + col] = f2bfn(acc[i][j][rr]);
            }
    }
}

// ---------------- GEMM 128^2 (m97 + T1 + T4 + granule permute): used for wo
template <int EPI>
__global__ __launch_bounds__(256) void gemm_bt(const u16* __restrict__ A, const u16* __restrict__ Bt,
                                               const float* __restrict__ bias,
                                               const float* __restrict__ res,
                                               u16* __restrict__ outb, float* __restrict__ outf,
                                               u16* __restrict__ poutb,
                                               int M, int N, int K) {
    __shared__ __align__(16) u16 As[3][4096];
    __shared__ __align__(16) u16 Bs[3][4096];
    const int tid = threadIdx.x;
    const int lane = tid & 63, wid = tid >> 6;
    const int g = lane >> 4, cl = lane & 15;
    const int wr = wid >> 1, wc = wid & 1;
    const int gx = gridDim.x;
    const int lid = blockIdx.y * gx + blockIdx.x;
    const int per8 = (gx * gridDim.y) >> 3;
    const int newlin = (lid & 7) * per8 + (lid >> 3);
    const int m0 = (newlin / gx) << 7;
    const int n0 = (newlin % gx) << 7;
    const int kchunk = K / gridDim.z;
    const int kbase = blockIdx.z * kchunk;
    const int NT = kchunk >> 5;
    f32x4 acc[4][4] = {};
    const int grow = tid >> 2;
    const int gcol = (tid & 3) ^ ((tid >> 3) & 3);

    auto stage = [&](int buf, int kt) {
        const int ko = kbase + (kt << 5);
        gl_lds16(A + (size_t)(m0 + grow) * K + ko + (gcol << 3),       &As[buf][wid << 9]);
        gl_lds16(A + (size_t)(m0 + grow + 64) * K + ko + (gcol << 3),  &As[buf][(wid << 9) + 2048]);
        gl_lds16(Bt + (size_t)(n0 + grow) * K + ko + (gcol << 3),      &Bs[buf][wid << 9]);
        gl_lds16(Bt + (size_t)(n0 + grow + 64) * K + ko + (gcol << 3), &Bs[buf][(wid << 9) + 2048]);
    };

    stage(0, 0);
    stage(1, 1);
    for (int kt = 0; kt < NT; ++kt) {
        if (kt + 1 < NT) asm volatile("s_waitcnt vmcnt(4)" ::: "memory");
        else             asm volatile("s_waitcnt vmcnt(0)" ::: "memory");
        __builtin_amdgcn_s_barrier();
        __builtin_amdgcn_sched_barrier(0);
        if (kt + 2 < NT) stage((kt + 2) % 3, kt + 2);
        const int cb = kt % 3;
        bf16x8 a[4], b[4];
        #pragma unroll
        for (int i = 0; i < 4; ++i) {
            int row = (wr << 6) + (i << 4) + cl;
            a[i] = *(const bf16x8*)&As[cb][((row << 2) + (g ^ ((row >> 1) & 3))) << 3];
        }
        #pragma unroll
        for (int j = 0; j < 4; ++j) {
            int row = (wc << 6) + (j << 4) + cl;
            b[j] = *(const bf16x8*)&Bs[cb][((row << 2) + (g ^ ((row >> 1) & 3))) << 3];
        }
        __builtin_amdgcn_s_setprio(1);
        #pragma unroll
        for (int i = 0; i < 4; ++i)
            #pragma unroll
            for (int j = 0; j < 4; ++j)
                acc[i][j] = __builtin_amdgcn_mfma_f32_16x16x32_bf16(a[i], b[j], acc[i][j], 0, 0, 0);
        __builtin_amdgcn_s_setprio(0);
    }
    if (blockIdx.z == 0) {
        #pragma unroll
        for (int i = 0; i < 4; ++i)
            #pragma unroll
            for (int j = 0; j < 4; ++j) {
                int row = m0 + (wr << 6) + (i << 4) + (g << 2);
                int col = n0 + (wc << 6) + (j << 4) + cl;
                float bc = bias[col];
                #pragma unroll
                for (int rr = 0; rr < 4; ++rr) {
                    float v = acc[i][j][rr] + bc;
                    size_t idx = (size_t)(row + rr) * N + col;
                    outf[idx] = v + res[idx];
                }
            }
    } else {
        const size_t pbase = (size_t)(blockIdx.z - 1) * ((size_t)M * N);
        #pragma unroll
        for (int i = 0; i < 4; ++i)
            #pragma unroll
            for (int j = 0; j < 4; ++j) {
                int row = m0 + (wr << 6) + (i << 4) + (g << 2);
                int col = n0 + (wc << 6) + (j << 4) + cl;
                #pragma unroll
                for (int rr = 0; rr < 4; ++rr)
                    poutb[pbase + (size_t)(row + rr) * N + col] = f2bfn(acc[i][j][rr]);
            }
    }
}

// ---------------- split-K reduce: out += sum of bf16 partials (each 4096*1024 elements)
__global__ __launch_bounds__(256) void reduce_addb(float* __restrict__ out, const u16* __restrict__ p,
                                                   int nparts) {
    int i = blockIdx.x * 256 + threadIdx.x;   // x4 elements
    float4 a = ((const float4*)out)[i];
    for (int j = 0; j < nparts; ++j) {
        u16x4 v = *(const u16x4*)(p + (size_t)j * 4194304 + ((size_t)i << 2));
        a.x += bf2f(v[0]); a.y += bf2f(v[1]); a.z += bf2f(v[2]); a.w += bf2f(v[3]);
    }
    ((float4*)out)[i] = a;
}

// ---------------- RoPE for q,k: qkv[4096][3072] -> qr/kr [BH][S][64]
// q pre-scaled by 0.125 * log2(e) so attention uses exp2 directly
__global__ __launch_bounds__(256) void rope_qk(const u16* __restrict__ qkv,
                                               const float* __restrict__ cost,
                                               const float* __restrict__ sint,
                                               u16* __restrict__ qr, u16* __restrict__ kr) {
    int tid = threadIdx.x;
    int rowid = (blockIdx.x << 4) + (tid >> 4);  // bh*2048+s over [0,65536)
    int j = tid & 15;
    int half = j >> 3, jj = j & 7;
    int b = rowid >> 15;
    int h = (rowid >> 11) & 15;
    int s = rowid & 2047;
    size_t qbase = (size_t)((b << 11) + s) * 3072 + (h << 6);
    float cf[4], sf_[4];
    {
        float4 c = *(const float4*)(cost + (s << 5) + (jj << 2));
        float4 sn = *(const float4*)(sint + (s << 5) + (jj << 2));
        cf[0] = c.x; cf[1] = c.y; cf[2] = c.z; cf[3] = c.w;
        sf_[0] = sn.x; sf_[1] = sn.y; sf_[2] = sn.z; sf_[3] = sn.w;
    }
    size_t obase = (size_t)rowid * 64 + (half << 5) + (jj << 2);
    {
        u16x8 v = *(const u16x8*)(qkv + qbase + (jj << 3));
        u16x4 o;
        #pragma unroll
        for (int m2 = 0; m2 < 4; ++m2) {
            float e = bf2f(v[2 * m2]), od = bf2f(v[2 * m2 + 1]);
            float val = (half == 0) ? (e * cf[m2] - od * sf_[m2]) : (e * sf_[m2] + od * cf[m2]);
            o[m2] = f2bfn(val * 0.1803368801f);  // 0.125 * log2(e)
        }
        *(u16x4*)(qr + obase) = o;
    }
    {
        u16x8 v = *(const u16x8*)(qkv + qbase + 1024 + (jj << 3));
        u16x4 o;
        #pragma unroll
        for (int m2 = 0; m2 < 4; ++m2) {
            float e = bf2f(v[2 * m2]), od = bf2f(v[2 * m2 + 1]);
            float val = (half == 0) ? (e * cf[m2] - od * sf_[m2]) : (e * sf_[m2] + od * cf[m2]);
            o[m2] = f2bfn(val);
        }
        *(u16x4*)(kr + obase) = o;
    }
}

// ---------------- V transpose: qkv v-part -> vt[BH][64 d][2048 s]
__global__ __launch_bounds__(256) void v_transpose(const u16* __restrict__ qkv,
                                                   u16* __restrict__ vt) {
    __shared__ __align__(16) u16 tl[64 * 80];
    int stile = blockIdx.x, bh = blockIdx.y;
    int b = bh >> 4, h = bh & 15;
    int tid = threadIdx.x;
    #pragma unroll
    for (int i = 0; i < 2; ++i) {
        int slot = tid + (i << 8);
        int srow = slot >> 3, c = slot & 7;
        u16x8 v = *(const u16x8*)(qkv + (size_t)((b << 11) + (stile << 6) + srow) * 3072 + 2048 + (h << 6) + (c << 3));
        *(u16x8*)(tl + srow * 80 + (c << 3)) = v;
    }
    __syncthreads();
    #pragma unroll
    for (int i = 0; i < 2; ++i) {
        int slot = tid + (i << 8);
        int drow = slot >> 3, c = slot & 7;
        u16x8 o;
        #pragma unroll
        for (int m2 = 0; m2 < 8; ++m2) o[m2] = tl[(c * 8 + m2) * 80 + drow];
        *(u16x8*)(vt + ((size_t)bh * 64 + drow) * 2048 + (stile << 6) + (c << 3)) = o;
    }
}

// ---------------- flash attention (best-measured R12 config): triangle-paired blocks with XCD
// head affinity, reg-staged double-buffered K/V (T14 issue-early/write-late, 1 barrier/tile),
// swapped QK^T, float mask, cvt_pk P-pack.
__global__ __launch_bounds__(256) void attn_kernel(const u16* __restrict__ Q, const u16* __restrict__ Kd,
                                                   const u16* __restrict__ Vt, const float* __restrict__ maskf,
                                                   u16* __restrict__ ctx) {
    __shared__ __align__(16) u16 Ks[2][4096];
    __shared__ __align__(16) u16 Vs[2][4096];
    __shared__ __align__(16) u16 Ps[4096];
    const int tid = threadIdx.x, lane = tid & 63, w = tid >> 6;
    const int g = lane >> 4, cl = lane & 15;
    const int lid = blockIdx.y * 16 + blockIdx.x;   // grid (16,32) = 512 blocks
    const int xcd = lid & 7, slot = lid >> 3;       // slot in [0,64)
    const int bh = xcd * 4 + (slot >> 4);           // 4 heads per XCD (K/V L2-resident)
    const int pair = slot & 15;                     // 16 pair-blocks per head
    const int b = bh >> 4, h = bh & 15;
    const u16* Kb = Kd + (size_t)bh * 2048 * 64;
    const u16* Vb = Vt + (size_t)bh * 64 * 2048;
    const int srow0 = tid >> 3, sc0 = tid & 7;
    const int srow1 = (tid + 256) >> 3, sc1 = sc0;
    bf16x8 onesb;
    #pragma unroll
    for (int i2 = 0; i2 < 8; ++i2) onesb[i2] = (__bf16)1.0f;
    // P write base: row = q = cl, 8B slot for (ct,g) at granule (ct*2+(g>>1)) ^ (cl&7)
    char* const pwb = (char*)Ps + w * 2048 + cl * 128 + ((g & 1) << 3);

    #pragma unroll
    for (int ci = 0; ci < 2; ++ci) {
        const int qb = (ci == 0) ? (31 - pair) : pair;  // heavy chunk first
        const size_t qoff = ((size_t)bh * 2048 + qb * 64 + w * 16 + cl) * 64;
        const bf16x8 qa0 = *(const bf16x8*)(Q + qoff + (g << 3));
        const bf16x8 qa1 = *(const bf16x8*)(Q + qoff + 32 + (g << 3));
        const int qrow = qb * 64 + w * 16 + cl;     // this lane's q row (S^T layout)
        f32x4 acc[4] = {};
        f32x4 lsum = {};

        u16x8 k0a = *(const u16x8*)(Kb + (size_t)srow0 * 64 + (sc0 << 3));
        u16x8 k0b = *(const u16x8*)(Kb + (size_t)srow1 * 64 + (sc1 << 3));
        u16x8 v0a = *(const u16x8*)(Vb + (size_t)srow0 * 2048 + (sc0 << 3));
        u16x8 v0b = *(const u16x8*)(Vb + (size_t)srow1 * 2048 + (sc1 << 3));
        __syncthreads();  // previous chunk's LDS readers done
        *(u16x8*)((char*)&Ks[0][0] + srow0 * 128 + ((sc0 ^ (srow0 & 7)) << 4)) = k0a;
        *(u16x8*)((char*)&Ks[0][0] + srow1 * 128 + ((sc1 ^ (srow1 & 7)) << 4)) = k0b;
        *(u16x8*)((char*)&Vs[0][0] + srow0 * 128 + ((sc0 ^ (srow0 & 7)) << 4)) = v0a;
        *(u16x8*)((char*)&Vs[0][0] + srow1 * 128 + ((sc1 ^ (srow1 & 7)) << 4)) = v0b;
        __syncthreads();

        int cur = 0;
        for (int t = 0; t <= qb; ++t) {
            const bool more = (t < qb);
            u16x8 rka, rkb, rva, rvb;
            if (more) {
                const u16* Kg = Kb + (size_t)(t + 1) * 64 * 64;
                rka = *(const u16x8*)(Kg + (size_t)srow0 * 64 + (sc0 << 3));
                rkb = *(const u16x8*)(Kg + (size_t)srow1 * 64 + (sc1 << 3));
                rva = *(const u16x8*)(Vb + (size_t)srow0 * 2048 + (t + 1) * 64 + (sc0 << 3));
                rvb = *(const u16x8*)(Vb + (size_t)srow1 * 2048 + (t + 1) * 64 + (sc1 << 3));
            }
            // swapped QK^T: sf[ct][rr] = S[q = qrow][k = t*64 + ct*16 + g*4 + rr]
            f32x4 sf[4];
            __builtin_amdgcn_s_setprio(1);
            #pragma unroll
            for (int ct = 0; ct < 4; ++ct) {
                f32x4 s = {};
                int krow = ct * 16 + cl;
                bf16x8 kb0 = *(const bf16x8*)((char*)&Ks[cur][0] + krow * 128 + ((g ^ (krow & 7)) << 4));
                bf16x8 kb1 = *(const bf16x8*)((char*)&Ks[cur][0] + krow * 128 + (((4 + g) ^ (krow & 7)) << 4));
                s = __builtin_amdgcn_mfma_f32_16x16x32_bf16(kb0, qa0, s, 0, 0, 0);
                s = __builtin_amdgcn_mfma_f32_16x16x32_bf16(kb1, qa1, s, 0, 0, 0);
                sf[ct] = s;
            }
            __builtin_amdgcn_s_setprio(0);
            // p = exp2(s) * mask * causal; pack 4 consecutive k as 2 cvt_pk -> one 8B write
            const bool diag = (t == qb);
            #pragma unroll
            for (int ct = 0; ct < 4; ++ct) {
                const int kc0 = t * 64 + ct * 16 + (g << 2);
                const float4 mv = *(const float4*)(maskf + (b << 11) + kc0);
                float p0 = exp2f(sf[ct][0]) * mv.x;
                float p1 = exp2f(sf[ct][1]) * mv.y;
                float p2 = exp2f(sf[ct][2]) * mv.z;
                float p3 = exp2f(sf[ct][3]) * mv.w;
                if (diag) {
                    p0 = (kc0 + 0 <= qrow) ? p0 : 0.0f;
                    p1 = (kc0 + 1 <= qrow) ? p1 : 0.0f;
                    p2 = (kc0 + 2 <= qrow) ? p2 : 0.0f;
                    p3 = (kc0 + 3 <= qrow) ? p3 : 0.0f;
                }
                u32 lo, hi;
                asm("v_cvt_pk_bf16_f32 %0, %1, %2" : "=v"(lo) : "v"(p0), "v"(p1));
                asm("v_cvt_pk_bf16_f32 %0, %1, %2" : "=v"(hi) : "v"(p2), "v"(p3));
                uint2 pk; pk.x = lo; pk.y = hi;
                *(uint2*)(pwb + ((((ct << 1) + (g >> 1)) ^ (cl & 7)) << 4)) = pk;
            }
            // PV + row-sum (ones-MFMA) from buf[cur]
            __builtin_amdgcn_s_setprio(1);
            #pragma unroll
            for (int kc = 0; kc < 2; ++kc) {
                bf16x8 pa = *(const bf16x8*)((char*)Ps + w * 2048 + cl * 128 + (((kc * 4 + g) ^ (cl & 7)) << 4));
                lsum = __builtin_amdgcn_mfma_f32_16x16x32_bf16(pa, onesb, lsum, 0, 0, 0);
                #pragma unroll
                for (int n = 0; n < 4; ++n) {
                    int vrow = n * 16 + cl;
                    bf16x8 vb = *(const bf16x8*)((char*)&Vs[cur][0] + vrow * 128 + (((kc * 4 + g) ^ (vrow & 7)) << 4));
                    acc[n] = __builtin_amdgcn_mfma_f32_16x16x32_bf16(pa, vb, acc[n], 0, 0, 0);
                }
            }
            __builtin_amdgcn_s_setprio(0);
            if (more) {
                *(u16x8*)((char*)&Ks[cur ^ 1][0] + srow0 * 128 + ((sc0 ^ (srow0 & 7)) << 4)) = rka;
                *(u16x8*)((char*)&Ks[cur ^ 1][0] + srow1 * 128 + ((sc1 ^ (srow1 & 7)) << 4)) = rkb;
                *(u16x8*)((char*)&Vs[cur ^ 1][0] + srow0 * 128 + ((sc0 ^ (srow0 & 7)) << 4)) = rva;
                *(u16x8*)((char*)&Vs[cur ^ 1][0] + srow1 * 128 + ((sc1 ^ (srow1 & 7)) << 4)) = rvb;
                __syncthreads();
            }
            cur ^= 1;
        }
        #pragma unroll
        for (int n = 0; n < 4; ++n)
            #pragma unroll
            for (int rr = 0; rr < 4; ++rr) {
                int token = (b << 11) + qb * 64 + w * 16 + g * 4 + rr;
                int col = (h << 6) + n * 16 + cl;
                ctx[(size_t)token * 1024 + col] = f2bfn(acc[n][rr] / lsum[rr]);
            }
    }
}

extern "C" void kernel_launch(void* const* d_in, const int* in_sizes, int n_in,
                              void* d_out, int out_size, void* d_ws, size_t ws_size,
                              hipStream_t stream) {
    const float* x   = (const float*)d_in[0];
    const int* mask  = (const int*)d_in[1];
    const float* wq  = (const float*)d_in[2];
    const float* bq  = (const float*)d_in[3];
    const float* wk  = (const float*)d_in[4];
    const float* bk  = (const float*)d_in[5];
    const float* wv  = (const float*)d_in[6];
    const float* bv  = (const float*)d_in[7];
    const float* wo  = (const float*)d_in[8];
    const float* bo  = (const float*)d_in[9];
    const float* w1  = (const float*)d_in[10];
    const float* b1  = (const float*)d_in[11];
    const float* w2  = (const float*)d_in[12];
    const float* b2  = (const float*)d_in[13];
    const float* g1  = (const float*)d_in[14];
    const float* be1 = (const float*)d_in[15];
    const float* g2  = (const float*)d_in[16];
    const float* be2 = (const float*)d_in[17];
    float* out = (float*)d_out;
    char* ws = (char*)d_ws;

    // ws map (109.59 MB total, overlays noted):
    u16* wqkvT  = (u16*)(ws + 0);            //  6 MB, whole call
    u16* woT    = (u16*)(ws + 6291456);      //  2 MB
    u16* w1T    = (u16*)(ws + 8388608);      //  8 MB
    u16* w2T    = (u16*)(ws + 16777216);     //  8 MB
    float* bqkv = (float*)(ws + 25165824);   // 12 KB
    float* cost = (float*)(ws + 25178112);   // 256 KB
    float* sint = (float*)(ws + 25440256);   // 256 KB
    u16* xn     = (u16*)(ws + 25702400);     //  8 MB (LN1 out; reused for LN2 out)
    float* x2   = (float*)(ws + 34091008);   // 16 MB (residual-2 base; first written by wo-gemm)
    float* maskf= (float*)(ws + 34091008);   // 16 KB overlay on x2 head (dead once wo-gemm writes x2)
    u16* qkv    = (u16*)(ws + 50868224);     // 24 MB (dead after v_transpose)
    u16* ffh    = (u16*)(ws + 50868224);     // 32 MB overlay on qkv+qr; spans to 84422656
    u16* qr     = (u16*)(ws + 76034048);     //  8 MB (dead after attn)
    u16* kr     = (u16*)(ws + 84422656);     //  8 MB (dead after attn)
    u16* vt     = (u16*)(ws + 92811264);     //  8 MB (dead after attn)
    u16* ctx    = (u16*)(ws + 101199872);    //  8 MB (dead after wo-gemm)
    // bf16 split-K partials: 3 x 8 MB on kr+vt+ctx. DISJOINT from ffh (ends 84422656).
    u16* partb  = (u16*)(ws + 84422656);

    transpose_cvt4<<<dim3(32, 32, 4), 256, 0, stream>>>(wq, wk, wv, wo,
                                                        wqkvT, wqkvT + 1024 * 1024, wqkvT + 2048 * 1024, woT);
    transpose_cvt2<<<dim3(128, 32, 2), 256, 0, stream>>>(w1, w2, w1T, w2T);
    prep_kernel<<<256, 256, 0, stream>>>(bq, bk, bv, bqkv, mask, maskf, cost, sint);

    ln_kernel<<<4096, 256, 0, stream>>>(x, g1, be1, xn);
    gemm256<0><<<dim3(12, 16), 512, 0, stream>>>(xn, wqkvT, bqkv, qkv, 4096, 3072, 1024);
    rope_qk<<<4096, 256, 0, stream>>>(qkv, cost, sint, qr, kr);
    v_transpose<<<dim3(32, 32), 256, 0, stream>>>(qkv, vt);
    attn_kernel<<<dim3(16, 32), 256, 0, stream>>>(qr, kr, vt, maskf, ctx);
    gemm_bt<1><<<dim3(8, 32, 2), 256, 0, stream>>>(ctx, woT, bo, x, nullptr, x2, partb, 4096, 1024, 1024);
    ln_fuse<<<4096, 256, 0, stream>>>(x2, partb, g2, be2, xn);
    gemm256<2><<<dim3(16, 16), 512, 0, stream>>>(xn, w1T, b1, ffh, 4096, 4096, 1024);
    gemm256r<<<dim3(4, 16, 4), 512, 0, stream>>>(ffh, w2T, b2, x2, out, partb, 4096, 1024, 4096);
    reduce_addb<<<4096, 256, 0, stream>>>(out, partb, 3);
}